// Round 13
// baseline (955.812 us; speedup 1.0000x reference)
//
#include <hip/hip_runtime.h>

#define R 5
#define U 100000
#define M 50000
#define E 2000000
#define F 10
#define D 50

#define TE (R * E)                      // 10,000,000 edges per direction
#define NBLK 1024                       // phase A/C block count (4/CU now)
#define CHUNK ((TE + NBLK - 1) / NBLK)  // 9766 edges per block
#define BSZ 256

// per-direction bucketing: user keys 128/bucket, item keys 64/bucket
// -> both bucket types average 2560 edges; NBU identical for both passes.
#define NKEY0 128
#define NKEY1 64
#define NBU 3907                        // 500000/128 = 250000/64
#define GT2 (NBU * NBLK)                // 4,000,768 scan cells per pass
#define NS1 ((GT2 + 1023) / 1024)       // 3907 scan blocks
#define S2K ((NS1 + 255) / 256)         // 16 entries/thread in scan2

#define CAP 3328                        // bucket staging cap (mean 2560 + 15 sigma)
#define ASTR 11                         // acc stride (gcd(11,32)=1)

// ===================== prep: f32 tables -> padded bf16 rows =====================
// row = 16 bf16 (32B, 32B-aligned): elems 0..9 = features (RNE), rest zero.
// Gather becomes dwordx4 + dword, always within one 64B line; tables 24MB total.
__global__ __launch_bounds__(BSZ) void prep_bf16(const float* __restrict__ src,
                                                 unsigned* __restrict__ dst,
                                                 int nrows) {
    int row = blockIdx.x * blockDim.x + threadIdx.x;
    if (row >= nrows) return;
    const float2* s2 = (const float2*)(src + (size_t)row * F);  // 8B-aligned (40B stride)
    unsigned w[5];
#pragma unroll
    for (int k = 0; k < 5; k++) {
        float2 v = s2[k];
        unsigned lo = __float_as_uint(v.x);
        unsigned hi = __float_as_uint(v.y);
        lo = (lo + 0x7FFFu + ((lo >> 16) & 1u)) >> 16;            // RNE bf16
        hi = (hi + 0x7FFFu + ((hi >> 16) & 1u)) & 0xFFFF0000u;
        w[k] = lo | hi;
    }
    uint4* d = (uint4*)(dst + (size_t)row * 8);
    d[0] = make_uint4(w[0], w[1], w[2], w[3]);
    d[1] = make_uint4(w[4], 0u, 0u, 0u);
}

// ===================== per-pass histogram =====================
template<int NN, int KSH>
__global__ __launch_bounds__(BSZ) void phaseA(const int* __restrict__ keys,
                                              unsigned* __restrict__ ghist) {
    __shared__ unsigned hist[NBU];
    for (int i = threadIdx.x; i < NBU; i += BSZ) hist[i] = 0;
    __syncthreads();
    int b = blockIdx.x;
    int lo = b * CHUNK, hi = min(lo + CHUNK, TE);
    for (int i = lo + threadIdx.x; i < hi; i += BSZ) {
        unsigned r = (unsigned)i / (unsigned)E;
        unsigned key = r * (unsigned)NN + (unsigned)keys[i];
        atomicAdd(&hist[key >> KSH], 1u);
    }
    __syncthreads();
    for (int j = threadIdx.x; j < NBU; j += BSZ)
        ghist[(size_t)j * NBLK + b] = hist[j];
}

// ===================== exclusive scan (in place), 3 kernels =====================
__global__ __launch_bounds__(BSZ) void scan1(unsigned* __restrict__ S,
                                             unsigned* __restrict__ psum) {
    __shared__ unsigned sh[BSZ];
    int base = blockIdx.x * 1024 + threadIdx.x * 4;
    unsigned v[4], tsum = 0;
    for (int k = 0; k < 4; k++) {
        int i = base + k;
        v[k] = (i < GT2) ? S[i] : 0u;
        tsum += v[k];
    }
    sh[threadIdx.x] = tsum;
    __syncthreads();
    for (int off = 1; off < BSZ; off <<= 1) {
        unsigned t = (threadIdx.x >= off) ? sh[threadIdx.x - off] : 0u;
        __syncthreads();
        sh[threadIdx.x] += t;
        __syncthreads();
    }
    unsigned ex = sh[threadIdx.x] - tsum;
    for (int k = 0; k < 4; k++) {
        int i = base + k;
        if (i < GT2) S[i] = ex;
        ex += v[k];
    }
    if (threadIdx.x == BSZ - 1) psum[blockIdx.x] = sh[BSZ - 1];
}

__global__ __launch_bounds__(BSZ) void scan2(unsigned* __restrict__ psum) {
    __shared__ unsigned sh[BSZ];
    unsigned v[S2K], tsum = 0;
    int base = threadIdx.x * S2K;
    for (int k = 0; k < S2K; k++) {
        int i = base + k;
        v[k] = (i < NS1) ? psum[i] : 0u;
        tsum += v[k];
    }
    sh[threadIdx.x] = tsum;
    __syncthreads();
    for (int off = 1; off < BSZ; off <<= 1) {
        unsigned t = (threadIdx.x >= off) ? sh[threadIdx.x - off] : 0u;
        __syncthreads();
        sh[threadIdx.x] += t;
        __syncthreads();
    }
    unsigned ex = sh[threadIdx.x] - tsum;
    for (int k = 0; k < S2K; k++) {
        int i = base + k;
        if (i < NS1) psum[i] = ex;
        ex += v[k];
    }
}

__global__ __launch_bounds__(BSZ) void scan3(unsigned* __restrict__ S,
                                             const unsigned* __restrict__ psum) {
    unsigned add = psum[blockIdx.x];
    int base = blockIdx.x * 1024 + threadIdx.x * 4;
    for (int k = 0; k < 4; k++) {
        int i = base + k;
        if (i < GT2) S[i] += add;
    }
}

// ===================== per-pass bucket scatter =====================
// payload = local(KSH bits) | other_id << KSH  (other_id < 2^17)
template<int NN, int KSH>
__global__ __launch_bounds__(BSZ) void phaseC(const int* __restrict__ keys,
                                              const int* __restrict__ other,
                                              const unsigned* __restrict__ S,
                                              unsigned* __restrict__ sorted) {
    __shared__ unsigned cur[NBU];
    int b = blockIdx.x;
    for (int j = threadIdx.x; j < NBU; j += BSZ)
        cur[j] = S[(size_t)j * NBLK + b];
    __syncthreads();
    int lo = b * CHUNK, hi = min(lo + CHUNK, TE);
    const unsigned KM = (1u << KSH) - 1u;
    for (int i = lo + threadIdx.x; i < hi; i += BSZ) {
        unsigned r = (unsigned)i / (unsigned)E;
        unsigned key = r * (unsigned)NN + (unsigned)keys[i];
        unsigned pos = atomicAdd(&cur[key >> KSH], 1u);
        sorted[pos] = (key & KM) | ((unsigned)other[i] << KSH);
    }
}

// bijective XCD swizzle within one direction's bucket range
__device__ __forceinline__ unsigned bucket_swizzle(unsigned o) {
    const unsigned q = NBU / 8u, rem = NBU % 8u;  // 488, 3
    unsigned x = o & 7u, off = o >> 3;
    return (x < rem ? x * (q + 1u) : rem * (q + 1u) + (x - rem) * q) + off;
}

// ===================== phaseD: sort-in-LDS + register reduce + projection ====
#define ADDROW(A, B)                                                        \
    do {                                                                    \
        A0 += __uint_as_float((A).x << 16);                                 \
        A1 += __uint_as_float((A).x & 0xFFFF0000u);                         \
        A2 += __uint_as_float((A).y << 16);                                 \
        A3 += __uint_as_float((A).y & 0xFFFF0000u);                         \
        A4 += __uint_as_float((A).z << 16);                                 \
        A5 += __uint_as_float((A).z & 0xFFFF0000u);                         \
        A6 += __uint_as_float((A).w << 16);                                 \
        A7 += __uint_as_float((A).w & 0xFFFF0000u);                         \
        A8 += __uint_as_float((B) << 16);                                   \
        A9 += __uint_as_float((B) & 0xFFFF0000u);                           \
    } while (0)

template<int N, int NSRC, int NKEY, int KSH>
__global__ __launch_bounds__(BSZ, 8) void phaseD(
    const unsigned* __restrict__ sorted, const unsigned* __restrict__ S,
    const unsigned* __restrict__ bsrc,    // padded bf16 table (R*NSRC rows x 8 u32)
    const float* __restrict__ fdst, const float* __restrict__ wsf,
    const float* __restrict__ wnf, const float* __restrict__ bia,
    float* __restrict__ out) {
    __shared__ unsigned sbuf[CAP];
    __shared__ float acc[NKEY0 * ASTR];
    __shared__ unsigned hist[NKEY0];
    __shared__ unsigned cur[NKEY0];
    __shared__ unsigned rbase[NKEY0];

    unsigned j = bucket_swizzle(blockIdx.x);
    const unsigned KM = (unsigned)NKEY - 1u;
    unsigned lo = S[(size_t)j * NBLK];
    unsigned hi = (j + 1 == NBU) ? (unsigned)TE : S[(size_t)(j + 1) * NBLK];
    unsigned len = hi - lo;
    unsigned keybase = j * (unsigned)NKEY;
    int tid = threadIdx.x;

    for (int t = tid; t < NKEY * ASTR; t += BSZ) acc[t] = 0.f;
    if (tid < NKEY) {
        hist[tid] = 0u;
        unsigned key = keybase + (unsigned)tid;
        unsigned r = (key < (unsigned)R * N) ? key / (unsigned)N : 0u;
        rbase[tid] = r * (unsigned)NSRC;
    }
    __syncthreads();

    if (len <= CAP) {
        // step 1: per-key histogram
        for (unsigned e = lo + tid; e < hi; e += BSZ)
            atomicAdd(&hist[sorted[e] & KM], 1u);
        __syncthreads();
        // step 2: exclusive scan (uniform barriers)
        if (tid < NKEY) cur[tid] = hist[tid];
        __syncthreads();
        for (int off = 1; off < NKEY; off <<= 1) {
            unsigned t = 0;
            if (tid < NKEY && tid >= off) t = cur[tid - off];
            __syncthreads();
            if (tid < NKEY && tid >= off) cur[tid] += t;
            __syncthreads();
        }
        if (tid < NKEY) cur[tid] -= hist[tid];
        __syncthreads();
        // step 3: key-sort into LDS
        for (unsigned e = lo + tid; e < hi; e += BSZ) {
            unsigned pay = sorted[e];
            unsigned pos = atomicAdd(&cur[pay & KM], 1u);
            sbuf[pos] = pay;
        }
        __syncthreads();
        // step 4: register segmented reduce (2-deep gather pipeline)
        unsigned L = (len + BSZ - 1) / BSZ;
        unsigned i0 = (unsigned)tid * L;
        unsigned i1 = min(i0 + L, len);
        if (i0 < i1) {
            int curKey = -1;
            float A0 = 0, A1 = 0, A2 = 0, A3 = 0, A4 = 0,
                  A5 = 0, A6 = 0, A7 = 0, A8 = 0, A9 = 0;
#define FLUSH_ACC()                                                        \
    do {                                                                   \
        if (curKey >= 0) {                                                 \
            float* ap = acc + curKey * ASTR;                               \
            atomicAdd(ap + 0, A0); atomicAdd(ap + 1, A1);                  \
            atomicAdd(ap + 2, A2); atomicAdd(ap + 3, A3);                  \
            atomicAdd(ap + 4, A4); atomicAdd(ap + 5, A5);                  \
            atomicAdd(ap + 6, A6); atomicAdd(ap + 7, A7);                  \
            atomicAdd(ap + 8, A8); atomicAdd(ap + 9, A9);                  \
        }                                                                  \
    } while (0)
#define ZERO_ACC() A0=A1=A2=A3=A4=A5=A6=A7=A8=A9=0.f
            unsigned i = i0;
            for (; i + 1 < i1; i += 2) {
                unsigned p0 = sbuf[i], p1 = sbuf[i + 1];
                unsigned k0 = p0 & KM, s0 = p0 >> KSH;
                unsigned k1 = p1 & KM, s1 = p1 >> KSH;
                const unsigned* r0 = bsrc + (size_t)(rbase[k0] + s0) * 8;
                const unsigned* r1 = bsrc + (size_t)(rbase[k1] + s1) * 8;
                uint4 xa = *(const uint4*)r0;
                unsigned xb = r0[4];
                uint4 ya = *(const uint4*)r1;
                unsigned yb = r1[4];
                if ((int)k0 != curKey) { FLUSH_ACC(); curKey = (int)k0; ZERO_ACC(); }
                ADDROW(xa, xb);
                if ((int)k1 != curKey) { FLUSH_ACC(); curKey = (int)k1; ZERO_ACC(); }
                ADDROW(ya, yb);
            }
            if (i < i1) {
                unsigned p0 = sbuf[i];
                unsigned k0 = p0 & KM, s0 = p0 >> KSH;
                const unsigned* r0 = bsrc + (size_t)(rbase[k0] + s0) * 8;
                uint4 xa = *(const uint4*)r0;
                unsigned xb = r0[4];
                if ((int)k0 != curKey) { FLUSH_ACC(); curKey = (int)k0; ZERO_ACC(); }
                ADDROW(xa, xb);
            }
            FLUSH_ACC();
#undef FLUSH_ACC
#undef ZERO_ACC
        }
    } else {
        // overflow fallback (statistically unreachable): per-edge atomics
        for (unsigned e = lo + tid; e < hi; e += BSZ) {
            unsigned pay = sorted[e];
            unsigned l = pay & KM, s = pay >> KSH;
            const unsigned* rp = bsrc + (size_t)(rbase[l] + s) * 8;
            uint4 a = *(const uint4*)rp;
            unsigned b = rp[4];
            float* ap = acc + l * ASTR;
            atomicAdd(ap + 0, __uint_as_float(a.x << 16));
            atomicAdd(ap + 1, __uint_as_float(a.x & 0xFFFF0000u));
            atomicAdd(ap + 2, __uint_as_float(a.y << 16));
            atomicAdd(ap + 3, __uint_as_float(a.y & 0xFFFF0000u));
            atomicAdd(ap + 4, __uint_as_float(a.z << 16));
            atomicAdd(ap + 5, __uint_as_float(a.z & 0xFFFF0000u));
            atomicAdd(ap + 6, __uint_as_float(a.w << 16));
            atomicAdd(ap + 7, __uint_as_float(a.w & 0xFFFF0000u));
            atomicAdd(ap + 8, __uint_as_float(b << 16));
            atomicAdd(ap + 9, __uint_as_float(b & 0xFFFF0000u));
            atomicAdd(&hist[l], 1u);
        }
    }
    __syncthreads();

    // epilogue: fused projection, count = hist
    int tot = NKEY * D;
    for (int o = tid; o < tot; o += BSZ) {
        int local = o / D, d = o - local * D;
        unsigned key = keybase + (unsigned)local;
        if (key >= (unsigned)R * N) continue;
        unsigned r = key / (unsigned)N, n = key - r * (unsigned)N;
        float inv = 1.f / fmaxf((float)hist[local], 1.f);
        const float* fd = fdst + ((size_t)r * N + n) * F;
        const float* a = acc + local * ASTR;
        const float* wsp = wsf + (size_t)r * F * D + d;
        const float* wnp = wnf + (size_t)r * F * D + d;
        float o1 = bia[r * D + d], o2 = 0.f;
#pragma unroll
        for (int f = 0; f < F; f++) {
            o1 += fd[f] * wsp[(size_t)f * D];
            o2 += a[f] * wnp[(size_t)f * D];
        }
        out[(size_t)n * (R * D) + r * D + d] = o1 + o2 * inv;
    }
}

// ======================= round-1 fallback (small ws) =======================
#define SUM_I_OFF 0
#define CNT_I_OFF ((size_t)R * M * F)
#define SUM_U_OFF (CNT_I_OFF + (size_t)R * M)
#define CNT_U_OFF (SUM_U_OFF + (size_t)R * U * F)
#define WS_FLOATS (CNT_U_OFF + (size_t)R * U)

__global__ void scatter_edges(const int* __restrict__ esrc, const int* __restrict__ edst,
                              const float* __restrict__ feat_u_fwd,
                              const float* __restrict__ feat_i_rev, float* __restrict__ ws) {
    float* sum_i = ws + SUM_I_OFF;
    float* cnt_i = ws + CNT_I_OFF;
    float* sum_u = ws + SUM_U_OFF;
    float* cnt_u = ws + CNT_U_OFF;
    const int total = R * E;
    for (int idx = blockIdx.x * blockDim.x + threadIdx.x; idx < total;
         idx += gridDim.x * blockDim.x) {
        int r = idx / E;
        int s = esrc[idx], d = edst[idx];
        const float* fu = feat_u_fwd + ((size_t)r * U + s) * F;
        const float* fi = feat_i_rev + ((size_t)r * M + d) * F;
        float* si = sum_i + ((size_t)r * M + d) * F;
        float* su = sum_u + ((size_t)r * U + s) * F;
#pragma unroll
        for (int f = 0; f < F; ++f) {
            atomicAdd(si + f, fu[f]);
            atomicAdd(su + f, fi[f]);
        }
        atomicAdd(cnt_i + (size_t)r * M + d, 1.0f);
        atomicAdd(cnt_u + (size_t)r * U + s, 1.0f);
    }
}

__global__ void finalize_nodes(int N, const float* __restrict__ feat_dst,
                               const float* __restrict__ w_self, const float* __restrict__ w_neigh,
                               const float* __restrict__ bias, const float* __restrict__ sum,
                               const float* __restrict__ cnt, float* __restrict__ out) {
    int idx = blockIdx.x * blockDim.x + threadIdx.x;
    int total = N * R * D;
    if (idx >= total) return;
    int n = idx / (R * D);
    int rd = idx - n * (R * D);
    int r = rd / D;
    int d = rd - r * D;
    const float* fd = feat_dst + ((size_t)r * N + n) * F;
    const float* sn = sum + ((size_t)r * N + n) * F;
    float inv = 1.0f / fmaxf(cnt[(size_t)r * N + n], 1.0f);
    const float* wsp = w_self + (size_t)r * F * D + d;
    const float* wnp = w_neigh + (size_t)r * F * D + d;
    float acc_self = bias[r * D + d];
    float acc_n = 0.0f;
#pragma unroll
    for (int f = 0; f < F; ++f) {
        acc_self += fd[f] * wsp[(size_t)f * D];
        acc_n += sn[f] * wnp[(size_t)f * D];
    }
    out[idx] = acc_self + acc_n * inv;
}

// ======================= launch =======================
extern "C" void kernel_launch(void* const* d_in, const int* in_sizes, int n_in,
                              void* d_out, int out_size, void* d_ws, size_t ws_size,
                              hipStream_t stream) {
    const int* edges_src = (const int*)d_in[0];
    const int* edges_dst = (const int*)d_in[1];
    const float* feat_u_fwd = (const float*)d_in[2];
    const float* feat_i_fwd = (const float*)d_in[3];
    const float* feat_i_rev = (const float*)d_in[4];
    const float* feat_u_rev = (const float*)d_in[5];
    const float* w_self_fwd = (const float*)d_in[6];
    const float* w_neigh_fwd = (const float*)d_in[7];
    const float* b_fwd = (const float*)d_in[8];
    const float* w_self_rev = (const float*)d_in[9];
    const float* w_neigh_rev = (const float*)d_in[10];
    const float* b_rev = (const float*)d_in[11];

    float* out = (float*)d_out;
    float* out_u = out;
    float* out_i = out + (size_t)U * R * D;

    // ws (u32): sorted TE | S GT2 | psum 4096 | bfu R*U*8 | bfi R*M*8  ~= 80.0 MB
    size_t o_S = (size_t)TE;
    size_t o_psum = o_S + GT2;
    size_t o_bfu = o_psum + 4096;
    size_t o_bfi = o_bfu + (size_t)R * U * 8;
    size_t tot_u32 = o_bfi + (size_t)R * M * 8;
    if (ws_size >= tot_u32 * 4ull) {
        unsigned* ws32 = (unsigned*)d_ws;
        unsigned* sorted = ws32;
        unsigned* S = ws32 + o_S;
        unsigned* psum = ws32 + o_psum;
        unsigned* bfu = ws32 + o_bfu;
        unsigned* bfi = ws32 + o_bfi;

        // prep: bf16 padded source tables
        prep_bf16<<<(R * U + BSZ - 1) / BSZ, BSZ, 0, stream>>>(feat_u_fwd, bfu, R * U);
        prep_bf16<<<(R * M + BSZ - 1) / BSZ, BSZ, 0, stream>>>(feat_i_rev, bfi, R * M);

        // pass 0: user-dst (rev conv). keys = r*U + esrc, gather item feats.
        phaseA<U, 7><<<NBLK, BSZ, 0, stream>>>(edges_src, S);
        scan1<<<NS1, BSZ, 0, stream>>>(S, psum);
        scan2<<<1, BSZ, 0, stream>>>(psum);
        scan3<<<NS1, BSZ, 0, stream>>>(S, psum);
        phaseC<U, 7><<<NBLK, BSZ, 0, stream>>>(edges_src, edges_dst, S, sorted);
        phaseD<U, M, NKEY0, 7><<<NBU, BSZ, 0, stream>>>(
            sorted, S, bfi, feat_u_rev, w_self_rev, w_neigh_rev, b_rev, out_u);

        // pass 1: item-dst (fwd conv). keys = r*M + edst, gather user feats.
        phaseA<M, 6><<<NBLK, BSZ, 0, stream>>>(edges_dst, S);
        scan1<<<NS1, BSZ, 0, stream>>>(S, psum);
        scan2<<<1, BSZ, 0, stream>>>(psum);
        scan3<<<NS1, BSZ, 0, stream>>>(S, psum);
        phaseC<M, 6><<<NBLK, BSZ, 0, stream>>>(edges_dst, edges_src, S, sorted);
        phaseD<M, U, NKEY1, 6><<<NBU, BSZ, 0, stream>>>(
            sorted, S, bfu, feat_i_fwd, w_self_fwd, w_neigh_fwd, b_fwd, out_i);
    } else {
        // fallback: round-1 global-atomic path
        float* ws = (float*)d_ws;
        hipMemsetAsync(d_ws, 0, WS_FLOATS * sizeof(float), stream);
        scatter_edges<<<4096, 256, 0, stream>>>(edges_src, edges_dst, feat_u_fwd, feat_i_rev, ws);
        finalize_nodes<<<(U * R * D + 255) / 256, 256, 0, stream>>>(
            U, feat_u_rev, w_self_rev, w_neigh_rev, b_rev, ws + SUM_U_OFF, ws + CNT_U_OFF, out_u);
        finalize_nodes<<<(M * R * D + 255) / 256, 256, 0, stream>>>(
            M, feat_i_fwd, w_self_fwd, w_neigh_fwd, b_fwd, ws + SUM_I_OFF, ws + CNT_I_OFF, out_i);
    }
}

// Round 14
// 755.270 us; speedup vs baseline: 1.2655x; 1.2655x over previous
//
#include <hip/hip_runtime.h>

#define R 5
#define U 100000
#define M 50000
#define E 2000000
#define F 10
#define D 50

#define TE (R * E)                      // 10,000,000 edges
#define NBLK 192                        // phaseB block count (region per block)
#define CHUNK ((TE + NBLK - 1) / NBLK)  // 52,084 edges per block
#define BSZ 256

// balanced buckets: user 128 keys (deg~20), item 64 keys (deg~40) -> ~2560 edges each
#define NKEY_U 128
#define NKEY_I 64
#define NBU_U ((R * U + NKEY_U - 1) / NKEY_U)  // 3907
#define NBU_I ((R * M + NKEY_I - 1) / NKEY_I)  // 3907
#define NBU_T (NBU_U + NBU_I)                  // 7814
#define GTOT (NBU_T * NBLK)                    // 1,500,288 segment starts
#define SCAN_PER ((NBU_T + BSZ - 1) / BSZ)     // 31 buckets per thread in B-scan

#define CAP 3328                        // bucket cap (mean 2560 + 15 sigma)
#define ASTR 11                         // acc stride (gcd(11,32)=1)

// ============== phaseB: fused histogram + in-LDS scan + bucket scatter ==============
// Each block owns edges [b*CHUNK, hi) and entry region [2*CHUNK*b, 2*CHUNK*b + 2*(hi-lo)).
// ghist[j*NBLK + b] = absolute start of bucket j's segment inside block b's region.
__global__ __launch_bounds__(BSZ) void phaseB(const int* __restrict__ esrc,
                                              const int* __restrict__ edst,
                                              unsigned* __restrict__ ghist,
                                              unsigned* __restrict__ sorted) {
    __shared__ unsigned hist[NBU_T];   // 31.3 KB: counts -> absolute cursors
    __shared__ unsigned wsum[BSZ];
    int b = blockIdx.x;
    int lo = b * CHUNK, hi = min(lo + CHUNK, TE);
    int tid = threadIdx.x;

    for (int i = tid; i < NBU_T; i += BSZ) hist[i] = 0;
    __syncthreads();
    // pass 1: per-block histogram over both key spaces
    for (int i = lo + tid; i < hi; i += BSZ) {
        unsigned r = (unsigned)i / (unsigned)E;
        unsigned ku = r * U + (unsigned)esrc[i];
        unsigned ki = r * M + (unsigned)edst[i];
        atomicAdd(&hist[ku >> 7], 1u);
        atomicAdd(&hist[NBU_U + (ki >> 6)], 1u);
    }
    __syncthreads();
    // in-LDS exclusive scan of hist[0..NBU_T): per-thread contiguous range + block scan
    unsigned s = 0;
    int base = tid * SCAN_PER;
    for (int k = 0; k < SCAN_PER; k++) {
        int idx = base + k;
        if (idx < NBU_T) s += hist[idx];
    }
    wsum[tid] = s;
    __syncthreads();
    for (int off = 1; off < BSZ; off <<= 1) {
        unsigned v = (tid >= off) ? wsum[tid - off] : 0u;
        __syncthreads();
        wsum[tid] += v;
        __syncthreads();
    }
    unsigned run = wsum[tid] - s;                       // exclusive prefix of this range
    unsigned regbase = 2u * (unsigned)CHUNK * (unsigned)b;
    for (int k = 0; k < SCAN_PER; k++) {
        int idx = base + k;
        if (idx < NBU_T) {
            unsigned h = hist[idx];
            unsigned absoff = regbase + run;
            hist[idx] = absoff;                         // becomes absolute cursor
            ghist[(size_t)idx * NBLK + b] = absoff;
            run += h;
        }
    }
    __syncthreads();
    // pass 2: scatter entries into this block's region (L2-local)
    for (int i = lo + tid; i < hi; i += BSZ) {
        unsigned r = (unsigned)i / (unsigned)E;
        int ss = esrc[i], dd = edst[i];
        unsigned ku = r * U + (unsigned)ss;
        unsigned ki = r * M + (unsigned)dd;
        unsigned p0 = atomicAdd(&hist[ku >> 7], 1u);
        sorted[p0] = (ku & 127u) | ((unsigned)dd << 7);
        unsigned p1 = atomicAdd(&hist[NBU_U + (ki >> 6)], 1u);
        sorted[p1] = (ki & 63u) | ((unsigned)ss << 6);
    }
}

// per-direction bijective XCD swizzle (NBU_U == NBU_I == 3907)
__device__ __forceinline__ unsigned bucket_swizzle(unsigned orig) {
    unsigned o = (orig < NBU_U) ? orig : orig - NBU_U;
    const unsigned q = NBU_U / 8u, rem = NBU_U % 8u;
    unsigned x = o & 7u, off = o >> 3;
    unsigned m = (x < rem ? x * (q + 1u) : rem * (q + 1u) + (x - rem) * q) + off;
    return (orig < NBU_U) ? m : NBU_U + m;
}

// ============== phaseD: stage-once + in-LDS sort + register reduce + projection ====
__global__ __launch_bounds__(BSZ, 4) void phaseD(
    const unsigned* __restrict__ sorted, const unsigned* __restrict__ ghist,
    const float* __restrict__ fsrc_u, const float* __restrict__ fdst_u,
    const float* __restrict__ wsf_u, const float* __restrict__ wnf_u,
    const float* __restrict__ bia_u,
    const float* __restrict__ fsrc_i, const float* __restrict__ fdst_i,
    const float* __restrict__ wsf_i, const float* __restrict__ wnf_i,
    const float* __restrict__ bia_i,
    float* __restrict__ out_u, float* __restrict__ out_i) {
    __shared__ unsigned sbuf[CAP];          // staged (arrival order)
    __shared__ unsigned sbuf2[CAP];         // key-sorted
    __shared__ float acc[NKEY_U * ASTR];
    __shared__ unsigned hist[NKEY_U];
    __shared__ unsigned cur[NKEY_U];
    __shared__ unsigned rbase[NKEY_U];
    __shared__ unsigned segst[NBLK];
    __shared__ unsigned segoff[NBLK + 1];

    unsigned bkt = bucket_swizzle(blockIdx.x);
    bool isU = bkt < NBU_U;
    unsigned N = isU ? U : M;
    unsigned NSRC = isU ? M : U;
    unsigned NKEY = isU ? NKEY_U : NKEY_I;
    unsigned KM = NKEY - 1u;
    unsigned KSH = isU ? 7u : 6u;
    const float* fsrc = isU ? fsrc_u : fsrc_i;
    unsigned jloc = isU ? bkt : bkt - NBU_U;
    unsigned keybase = jloc * NKEY;
    int tid = threadIdx.x;

    for (int t = tid; t < NKEY_U * ASTR; t += BSZ) acc[t] = 0.f;
    if (tid < NKEY_U) {
        hist[tid] = 0u;
        unsigned key = keybase + (unsigned)tid;
        unsigned r = (key < (unsigned)R * N) ? key / N : 0u;
        rbase[tid] = r * NSRC;
    }
    // segment descriptors: start + count per source block
    unsigned c = 0;
    if (tid < NBLK) {
        unsigned st = ghist[(size_t)bkt * NBLK + tid];
        unsigned en;
        if (bkt + 1 < (unsigned)NBU_T) en = ghist[(size_t)(bkt + 1) * NBLK + tid];
        else en = min(2u * (unsigned)CHUNK * (unsigned)(tid + 1), 2u * (unsigned)TE);
        segst[tid] = st;
        c = en - st;
        segoff[tid] = c;
    }
    __syncthreads();
    // exclusive scan of 192 counts (Hillis-Steele, uniform barriers)
    for (int off = 1; off < NBLK; off <<= 1) {
        unsigned v = 0;
        if (tid < NBLK && tid >= off) v = segoff[tid - off];
        __syncthreads();
        if (tid < NBLK && tid >= off) segoff[tid] += v;
        __syncthreads();
    }
    if (tid < NBLK) segoff[tid] -= c;
    if (tid == NBLK - 1) segoff[NBLK] = segoff[tid] + c;
    __syncthreads();
    unsigned len = segoff[NBLK];

    if (len <= CAP) {
        // stage once: thread t copies its block's contiguous segment
        if (tid < NBLK) {
            unsigned dst = segoff[tid], st = segst[tid];
            for (unsigned k = 0; k < c; k++) sbuf[dst + k] = sorted[st + k];
        }
        __syncthreads();
        // step 1: per-key histogram from LDS
        for (unsigned e = tid; e < len; e += BSZ)
            atomicAdd(&hist[sbuf[e] & KM], 1u);
        __syncthreads();
        // step 2: exclusive scan of hist -> cur
        if (tid < NKEY) cur[tid] = hist[tid];
        __syncthreads();
        for (int off = 1; off < (int)NKEY; off <<= 1) {
            unsigned t2 = 0;
            if (tid < (int)NKEY && tid >= off) t2 = cur[tid - off];
            __syncthreads();
            if (tid < (int)NKEY && tid >= off) cur[tid] += t2;
            __syncthreads();
        }
        if (tid < (int)NKEY) cur[tid] -= hist[tid];
        __syncthreads();
        // step 3: key-sort sbuf -> sbuf2
        for (unsigned e = tid; e < len; e += BSZ) {
            unsigned pay = sbuf[e];
            unsigned pos = atomicAdd(&cur[pay & KM], 1u);
            sbuf2[pos] = pay;
        }
        __syncthreads();
        // step 4: register segmented reduce over equal slices
        unsigned L = (len + BSZ - 1) / BSZ;
        unsigned i0 = (unsigned)tid * L;
        unsigned i1 = min(i0 + L, len);
        if (i0 < i1) {
            int curKey = -1;
            float A0 = 0, A1 = 0, A2 = 0, A3 = 0, A4 = 0,
                  A5 = 0, A6 = 0, A7 = 0, A8 = 0, A9 = 0;
#define FLUSH_ACC()                                                        \
    do {                                                                   \
        if (curKey >= 0) {                                                 \
            float* ap = acc + curKey * ASTR;                               \
            atomicAdd(ap + 0, A0); atomicAdd(ap + 1, A1);                  \
            atomicAdd(ap + 2, A2); atomicAdd(ap + 3, A3);                  \
            atomicAdd(ap + 4, A4); atomicAdd(ap + 5, A5);                  \
            atomicAdd(ap + 6, A6); atomicAdd(ap + 7, A7);                  \
            atomicAdd(ap + 8, A8); atomicAdd(ap + 9, A9);                  \
        }                                                                  \
    } while (0)
#define ZERO_ACC() A0=A1=A2=A3=A4=A5=A6=A7=A8=A9=0.f
            unsigned i = i0;
            for (; i + 1 < i1; i += 2) {
                unsigned p0 = sbuf2[i], p1 = sbuf2[i + 1];
                unsigned k0 = p0 & KM, s0 = p0 >> KSH;
                unsigned k1 = p1 & KM, s1 = p1 >> KSH;
                const float2* r0 = (const float2*)(fsrc + (size_t)(rbase[k0] + s0) * F);
                const float2* r1 = (const float2*)(fsrc + (size_t)(rbase[k1] + s1) * F);
                float2 x0 = r0[0], x1 = r0[1], x2 = r0[2], x3 = r0[3], x4 = r0[4];
                float2 y0 = r1[0], y1 = r1[1], y2 = r1[2], y3 = r1[3], y4 = r1[4];
                if ((int)k0 != curKey) { FLUSH_ACC(); curKey = (int)k0; ZERO_ACC(); }
                A0 += x0.x; A1 += x0.y; A2 += x1.x; A3 += x1.y; A4 += x2.x;
                A5 += x2.y; A6 += x3.x; A7 += x3.y; A8 += x4.x; A9 += x4.y;
                if ((int)k1 != curKey) { FLUSH_ACC(); curKey = (int)k1; ZERO_ACC(); }
                A0 += y0.x; A1 += y0.y; A2 += y1.x; A3 += y1.y; A4 += y2.x;
                A5 += y2.y; A6 += y3.x; A7 += y3.y; A8 += y4.x; A9 += y4.y;
            }
            if (i < i1) {
                unsigned p0 = sbuf2[i];
                unsigned k0 = p0 & KM, s0 = p0 >> KSH;
                const float2* r0 = (const float2*)(fsrc + (size_t)(rbase[k0] + s0) * F);
                float2 x0 = r0[0], x1 = r0[1], x2 = r0[2], x3 = r0[3], x4 = r0[4];
                if ((int)k0 != curKey) { FLUSH_ACC(); curKey = (int)k0; ZERO_ACC(); }
                A0 += x0.x; A1 += x0.y; A2 += x1.x; A3 += x1.y; A4 += x2.x;
                A5 += x2.y; A6 += x3.x; A7 += x3.y; A8 += x4.x; A9 += x4.y;
            }
            FLUSH_ACC();
#undef FLUSH_ACC
#undef ZERO_ACC
        }
    } else {
        // overflow fallback (statistically unreachable): per-edge LDS atomics
        if (tid < NBLK) {
            unsigned st = segst[tid];
            for (unsigned k = 0; k < c; k++) {
                unsigned pay = sorted[st + k];
                unsigned l = pay & KM, ssrc = pay >> KSH;
                const float2* row = (const float2*)(fsrc + (size_t)(rbase[l] + ssrc) * F);
                float* ap = acc + l * ASTR;
#pragma unroll
                for (int k2 = 0; k2 < 5; k2++) {
                    float2 v = row[k2];
                    atomicAdd(ap + 2 * k2, v.x);
                    atomicAdd(ap + 2 * k2 + 1, v.y);
                }
                atomicAdd(&hist[l], 1u);
            }
        }
    }
    __syncthreads();

    // epilogue: fused projection
    const float* fdst = isU ? fdst_u : fdst_i;
    const float* wsf = isU ? wsf_u : wsf_i;
    const float* wnf = isU ? wnf_u : wnf_i;
    const float* bia = isU ? bia_u : bia_i;
    float* out = isU ? out_u : out_i;

    int tot = (int)NKEY * D;
    for (int o = tid; o < tot; o += BSZ) {
        int local = o / D, d = o - local * D;
        unsigned key = keybase + (unsigned)local;
        if (key >= (unsigned)R * N) continue;
        unsigned r = key / N, n = key - r * N;
        float inv = 1.f / fmaxf((float)hist[local], 1.f);
        const float* fd = fdst + ((size_t)r * N + n) * F;
        const float* a = acc + local * ASTR;
        const float* wsp = wsf + (size_t)r * F * D + d;
        const float* wnp = wnf + (size_t)r * F * D + d;
        float o1 = bia[r * D + d], o2 = 0.f;
#pragma unroll
        for (int f = 0; f < F; f++) {
            o1 += fd[f] * wsp[(size_t)f * D];
            o2 += a[f] * wnp[(size_t)f * D];
        }
        out[(size_t)n * (R * D) + r * D + d] = o1 + o2 * inv;
    }
}

// ======================= round-1 fallback (small ws) =======================
#define SUM_I_OFF 0
#define CNT_I_OFF ((size_t)R * M * F)
#define SUM_U_OFF (CNT_I_OFF + (size_t)R * M)
#define CNT_U_OFF (SUM_U_OFF + (size_t)R * U * F)
#define WS_FLOATS (CNT_U_OFF + (size_t)R * U)

__global__ void scatter_edges(const int* __restrict__ esrc, const int* __restrict__ edst,
                              const float* __restrict__ feat_u_fwd,
                              const float* __restrict__ feat_i_rev, float* __restrict__ ws) {
    float* sum_i = ws + SUM_I_OFF;
    float* cnt_i = ws + CNT_I_OFF;
    float* sum_u = ws + SUM_U_OFF;
    float* cnt_u = ws + CNT_U_OFF;
    const int total = R * E;
    for (int idx = blockIdx.x * blockDim.x + threadIdx.x; idx < total;
         idx += gridDim.x * blockDim.x) {
        int r = idx / E;
        int s = esrc[idx], d = edst[idx];
        const float* fu = feat_u_fwd + ((size_t)r * U + s) * F;
        const float* fi = feat_i_rev + ((size_t)r * M + d) * F;
        float* si = sum_i + ((size_t)r * M + d) * F;
        float* su = sum_u + ((size_t)r * U + s) * F;
#pragma unroll
        for (int f = 0; f < F; ++f) {
            atomicAdd(si + f, fu[f]);
            atomicAdd(su + f, fi[f]);
        }
        atomicAdd(cnt_i + (size_t)r * M + d, 1.0f);
        atomicAdd(cnt_u + (size_t)r * U + s, 1.0f);
    }
}

__global__ void finalize_nodes(int N, const float* __restrict__ feat_dst,
                               const float* __restrict__ w_self, const float* __restrict__ w_neigh,
                               const float* __restrict__ bias, const float* __restrict__ sum,
                               const float* __restrict__ cnt, float* __restrict__ out) {
    int idx = blockIdx.x * blockDim.x + threadIdx.x;
    int total = N * R * D;
    if (idx >= total) return;
    int n = idx / (R * D);
    int rd = idx - n * (R * D);
    int r = rd / D;
    int d = rd - r * D;
    const float* fd = feat_dst + ((size_t)r * N + n) * F;
    const float* sn = sum + ((size_t)r * N + n) * F;
    float inv = 1.0f / fmaxf(cnt[(size_t)r * N + n], 1.0f);
    const float* wsp = w_self + (size_t)r * F * D + d;
    const float* wnp = w_neigh + (size_t)r * F * D + d;
    float acc_self = bias[r * D + d];
    float acc_n = 0.0f;
#pragma unroll
    for (int f = 0; f < F; ++f) {
        acc_self += fd[f] * wsp[(size_t)f * D];
        acc_n += sn[f] * wnp[(size_t)f * D];
    }
    out[idx] = acc_self + acc_n * inv;
}

// ======================= launch =======================
extern "C" void kernel_launch(void* const* d_in, const int* in_sizes, int n_in,
                              void* d_out, int out_size, void* d_ws, size_t ws_size,
                              hipStream_t stream) {
    const int* edges_src = (const int*)d_in[0];
    const int* edges_dst = (const int*)d_in[1];
    const float* feat_u_fwd = (const float*)d_in[2];
    const float* feat_i_fwd = (const float*)d_in[3];
    const float* feat_i_rev = (const float*)d_in[4];
    const float* feat_u_rev = (const float*)d_in[5];
    const float* w_self_fwd = (const float*)d_in[6];
    const float* w_neigh_fwd = (const float*)d_in[7];
    const float* b_fwd = (const float*)d_in[8];
    const float* w_self_rev = (const float*)d_in[9];
    const float* w_neigh_rev = (const float*)d_in[10];
    const float* b_rev = (const float*)d_in[11];

    float* out = (float*)d_out;
    float* out_u = out;
    float* out_i = out + (size_t)U * R * D;

    // ws (u32): sorted 2*TE | ghist GTOT   = 86.0 MB (same as proven budget)
    size_t need = ((size_t)2 * TE + (size_t)GTOT) * 4ull;
    if (ws_size >= need) {
        unsigned* sorted = (unsigned*)d_ws;
        unsigned* ghist = sorted + (size_t)2 * TE;

        phaseB<<<NBLK, BSZ, 0, stream>>>(edges_src, edges_dst, ghist, sorted);
        phaseD<<<NBU_T, BSZ, 0, stream>>>(sorted, ghist,
                                          feat_i_rev, feat_u_rev, w_self_rev, w_neigh_rev, b_rev,
                                          feat_u_fwd, feat_i_fwd, w_self_fwd, w_neigh_fwd, b_fwd,
                                          out_u, out_i);
    } else {
        // fallback: round-1 global-atomic path
        float* ws = (float*)d_ws;
        hipMemsetAsync(d_ws, 0, WS_FLOATS * sizeof(float), stream);
        scatter_edges<<<4096, 256, 0, stream>>>(edges_src, edges_dst, feat_u_fwd, feat_i_rev, ws);
        finalize_nodes<<<(U * R * D + 255) / 256, 256, 0, stream>>>(
            U, feat_u_rev, w_self_rev, w_neigh_rev, b_rev, ws + SUM_U_OFF, ws + CNT_U_OFF, out_u);
        finalize_nodes<<<(M * R * D + 255) / 256, 256, 0, stream>>>(
            M, feat_i_fwd, w_self_fwd, w_neigh_fwd, b_fwd, ws + SUM_I_OFF, ws + CNT_I_OFF, out_i);
    }
}

// Round 15
// 752.190 us; speedup vs baseline: 1.2707x; 1.0041x over previous
//
#include <hip/hip_runtime.h>

#define R 5
#define U 100000
#define M 50000
#define E 2000000
#define F 10
#define D 50

#define TE (R * E)                      // 10,000,000 edges per direction
#define NBLK 192                        // phase A/C block count (ws fits 86MB)
#define CHUNK ((TE + NBLK - 1) / NBLK)  // 52,084 edges per block
#define BSZ 256

// balanced buckets: user avg degree 20, item avg degree 40 -> equal edges/bucket
#define NKEY_U 128
#define NKEY_I 64
#define KS_U (R * U)
#define KS_I (R * M)
#define NBU_U ((KS_U + NKEY_U - 1) / NKEY_U)  // 3907
#define NBU_I ((KS_I + NKEY_I - 1) / NKEY_I)  // 3907
#define NBU_T (NBU_U + NBU_I)                 // 7814
#define OFFI (NBU_U * NBLK)
#define GTOT (OFFI + NBU_I * NBLK)            // 1,500,288
#define NS1 ((GTOT + 1023) / 1024)
#define S2K ((NS1 + 255) / 256)

#define CAP 3328                        // max edges/bucket (mean 2560 + 15 sigma)
#define ASTR 11                         // acc stride (gcd(11,32)=1)

// ======================= bucketed counting-sort path =======================

__global__ __launch_bounds__(BSZ) void phaseA(const int* __restrict__ esrc,
                                              const int* __restrict__ edst,
                                              unsigned* __restrict__ ghist) {
    __shared__ unsigned hist[NBU_T];
    for (int i = threadIdx.x; i < NBU_T; i += BSZ) hist[i] = 0;
    __syncthreads();
    int b = blockIdx.x;
    int lo = b * CHUNK, hi = min(lo + CHUNK, TE);
    for (int i = lo + threadIdx.x; i < hi; i += BSZ) {
        unsigned r = (unsigned)i / (unsigned)E;
        int s = esrc[i], d = edst[i];
        unsigned ku = r * U + (unsigned)s;
        unsigned ki = r * M + (unsigned)d;
        atomicAdd(&hist[ku >> 7], 1u);
        atomicAdd(&hist[NBU_U + (ki >> 6)], 1u);
    }
    __syncthreads();
    for (int j = threadIdx.x; j < NBU_T; j += BSZ) {
        unsigned idx = (j < NBU_U) ? (unsigned)j * NBLK + b
                                   : OFFI + (unsigned)(j - NBU_U) * NBLK + b;
        ghist[idx] = hist[j];
    }
}

__global__ __launch_bounds__(BSZ) void scan1(unsigned* __restrict__ S,
                                             unsigned* __restrict__ psum) {
    __shared__ unsigned sh[BSZ];
    int base = blockIdx.x * 1024 + threadIdx.x * 4;
    unsigned v[4], tsum = 0;
    for (int k = 0; k < 4; k++) {
        int i = base + k;
        v[k] = (i < GTOT) ? S[i] : 0u;
        tsum += v[k];
    }
    sh[threadIdx.x] = tsum;
    __syncthreads();
    for (int off = 1; off < BSZ; off <<= 1) {
        unsigned t = (threadIdx.x >= off) ? sh[threadIdx.x - off] : 0u;
        __syncthreads();
        sh[threadIdx.x] += t;
        __syncthreads();
    }
    unsigned ex = sh[threadIdx.x] - tsum;
    for (int k = 0; k < 4; k++) {
        int i = base + k;
        if (i < GTOT) S[i] = ex;
        ex += v[k];
    }
    if (threadIdx.x == BSZ - 1) psum[blockIdx.x] = sh[BSZ - 1];
}

__global__ __launch_bounds__(BSZ) void scan2(unsigned* __restrict__ psum) {
    __shared__ unsigned sh[BSZ];
    unsigned v[S2K], tsum = 0;
    int base = threadIdx.x * S2K;
    for (int k = 0; k < S2K; k++) {
        int i = base + k;
        v[k] = (i < NS1) ? psum[i] : 0u;
        tsum += v[k];
    }
    sh[threadIdx.x] = tsum;
    __syncthreads();
    for (int off = 1; off < BSZ; off <<= 1) {
        unsigned t = (threadIdx.x >= off) ? sh[threadIdx.x - off] : 0u;
        __syncthreads();
        sh[threadIdx.x] += t;
        __syncthreads();
    }
    unsigned ex = sh[threadIdx.x] - tsum;
    for (int k = 0; k < S2K; k++) {
        int i = base + k;
        if (i < NS1) psum[i] = ex;
        ex += v[k];
    }
}

__global__ __launch_bounds__(BSZ) void scan3(unsigned* __restrict__ S,
                                             const unsigned* __restrict__ psum) {
    unsigned add = psum[blockIdx.x];
    int base = blockIdx.x * 1024 + threadIdx.x * 4;
    for (int k = 0; k < 4; k++) {
        int i = base + k;
        if (i < GTOT) S[i] += add;
    }
}

// user payload = local(7b) | item_id<<7 ; item payload = local(6b) | user_id<<6
__global__ __launch_bounds__(BSZ) void phaseC(const int* __restrict__ esrc,
                                              const int* __restrict__ edst,
                                              const unsigned* __restrict__ S,
                                              unsigned* __restrict__ sorted) {
    __shared__ unsigned cur[NBU_T];
    int b = blockIdx.x;
    for (int j = threadIdx.x; j < NBU_T; j += BSZ) {
        unsigned idx = (j < NBU_U) ? (unsigned)j * NBLK + b
                                   : OFFI + (unsigned)(j - NBU_U) * NBLK + b;
        cur[j] = S[idx];
    }
    __syncthreads();
    int lo = b * CHUNK, hi = min(lo + CHUNK, TE);
    for (int i = lo + threadIdx.x; i < hi; i += BSZ) {
        unsigned r = (unsigned)i / (unsigned)E;
        int s = esrc[i], d = edst[i];
        unsigned ku = r * U + (unsigned)s;
        unsigned ki = r * M + (unsigned)d;
        unsigned pu = atomicAdd(&cur[ku >> 7], 1u);
        sorted[pu] = (ku & 127u) | ((unsigned)d << 7);
        unsigned pi = atomicAdd(&cur[NBU_U + (ki >> 6)], 1u);
        sorted[pi] = (ki & 63u) | ((unsigned)s << 6);
    }
}

// phaseD v6 = v5 with 4-deep gather ILP in step 4 (the round-15 experiment:
// is the reduce core latency/ILP-bound or outstanding-request-capped?)
__global__ __launch_bounds__(BSZ, 8) void phaseD(
    const unsigned* __restrict__ sorted, const unsigned* __restrict__ S,
    const float* __restrict__ fsrc_u, const float* __restrict__ fdst_u,
    const float* __restrict__ wsf_u, const float* __restrict__ wnf_u,
    const float* __restrict__ bia_u,
    const float* __restrict__ fsrc_i, const float* __restrict__ fdst_i,
    const float* __restrict__ wsf_i, const float* __restrict__ wnf_i,
    const float* __restrict__ bia_i,
    float* __restrict__ out_u, float* __restrict__ out_i) {
    __shared__ unsigned sbuf[CAP];
    __shared__ float acc[NKEY_U * ASTR];
    __shared__ unsigned hist[NKEY_U];
    __shared__ unsigned cur[NKEY_U];
    __shared__ unsigned rbase[NKEY_U];

    // per-direction bijective XCD swizzle (NBU_U == NBU_I == 3907)
    unsigned orig = blockIdx.x;
    unsigned bkt;
    {
        unsigned o = (orig < NBU_U) ? orig : orig - NBU_U;
        const unsigned q = NBU_U / 8u, rem = NBU_U % 8u;
        unsigned x = o & 7u, off = o >> 3;
        unsigned m = (x < rem ? x * (q + 1u) : rem * (q + 1u) + (x - rem) * q) + off;
        bkt = (orig < NBU_U) ? m : NBU_U + m;
    }

    bool isU = bkt < NBU_U;
    int j = isU ? (int)bkt : (int)bkt - NBU_U;
    unsigned N = isU ? U : M;
    unsigned NSRC = isU ? M : U;
    unsigned NKEY = isU ? NKEY_U : NKEY_I;
    unsigned KM = NKEY - 1u;
    unsigned KSH = isU ? 7u : 6u;
    const float* fsrc = isU ? fsrc_u : fsrc_i;

    unsigned sbase = isU ? 0u : (unsigned)OFFI;
    unsigned lo = S[sbase + (unsigned)j * NBLK];
    unsigned hi = (!isU && j + 1 == NBU_I) ? (unsigned)(2 * TE)
                                           : S[sbase + (unsigned)(j + 1) * NBLK];
    unsigned len = hi - lo;
    unsigned keybase = (unsigned)j * NKEY;
    int tid = threadIdx.x;

    for (int t = tid; t < NKEY_U * ASTR; t += BSZ) acc[t] = 0.f;
    if (tid < NKEY_U) {
        hist[tid] = 0u;
        unsigned key = keybase + (unsigned)tid;
        unsigned r = (key < (unsigned)R * N) ? key / N : 0u;
        rbase[tid] = r * NSRC;
    }
    __syncthreads();

    if (len <= CAP) {
        // step 1: per-key histogram
        for (unsigned e = lo + tid; e < hi; e += BSZ)
            atomicAdd(&hist[sorted[e] & KM], 1u);
        __syncthreads();
        // step 2: exclusive scan of hist -> cur
        if (tid < NKEY) cur[tid] = hist[tid];
        __syncthreads();
        for (int off = 1; off < (int)NKEY; off <<= 1) {
            unsigned t = 0;
            if (tid < (int)NKEY && tid >= off) t = cur[tid - off];
            __syncthreads();
            if (tid < (int)NKEY && tid >= off) cur[tid] += t;
            __syncthreads();
        }
        if (tid < (int)NKEY) cur[tid] -= hist[tid];
        __syncthreads();
        // step 3: key-sort into LDS
        for (unsigned e = lo + tid; e < hi; e += BSZ) {
            unsigned pay = sorted[e];
            unsigned pos = atomicAdd(&cur[pay & KM], 1u);
            sbuf[pos] = pay;
        }
        __syncthreads();
        // step 4: register segmented reduce, 4-deep gather pipeline
        unsigned L = (len + BSZ - 1) / BSZ;
        unsigned i0 = (unsigned)tid * L;
        unsigned i1 = min(i0 + L, len);
        if (i0 < i1) {
            int curKey = -1;
            float A0 = 0, A1 = 0, A2 = 0, A3 = 0, A4 = 0,
                  A5 = 0, A6 = 0, A7 = 0, A8 = 0, A9 = 0;
#define FLUSH_ACC()                                                        \
    do {                                                                   \
        if (curKey >= 0) {                                                 \
            float* ap = acc + curKey * ASTR;                               \
            atomicAdd(ap + 0, A0); atomicAdd(ap + 1, A1);                  \
            atomicAdd(ap + 2, A2); atomicAdd(ap + 3, A3);                  \
            atomicAdd(ap + 4, A4); atomicAdd(ap + 5, A5);                  \
            atomicAdd(ap + 6, A6); atomicAdd(ap + 7, A7);                  \
            atomicAdd(ap + 8, A8); atomicAdd(ap + 9, A9);                  \
        }                                                                  \
    } while (0)
#define ZERO_ACC() A0=A1=A2=A3=A4=A5=A6=A7=A8=A9=0.f
#define ACCUM(V)                                                           \
    do {                                                                   \
        A0 += (V)[0].x; A1 += (V)[0].y; A2 += (V)[1].x; A3 += (V)[1].y;    \
        A4 += (V)[2].x; A5 += (V)[2].y; A6 += (V)[3].x; A7 += (V)[3].y;    \
        A8 += (V)[4].x; A9 += (V)[4].y;                                    \
    } while (0)
            unsigned i = i0;
            for (; i + 3 < i1; i += 4) {
                unsigned p0 = sbuf[i], p1 = sbuf[i + 1];
                unsigned p2 = sbuf[i + 2], p3 = sbuf[i + 3];
                unsigned k0 = p0 & KM, k1 = p1 & KM, k2 = p2 & KM, k3 = p3 & KM;
                const float2* r0 = (const float2*)(fsrc + (size_t)(rbase[k0] + (p0 >> KSH)) * F);
                const float2* r1 = (const float2*)(fsrc + (size_t)(rbase[k1] + (p1 >> KSH)) * F);
                const float2* r2 = (const float2*)(fsrc + (size_t)(rbase[k2] + (p2 >> KSH)) * F);
                const float2* r3 = (const float2*)(fsrc + (size_t)(rbase[k3] + (p3 >> KSH)) * F);
                float2 v0[5], v1[5], v2[5], v3[5];
#pragma unroll
                for (int k = 0; k < 5; k++) v0[k] = r0[k];
#pragma unroll
                for (int k = 0; k < 5; k++) v1[k] = r1[k];
#pragma unroll
                for (int k = 0; k < 5; k++) v2[k] = r2[k];
#pragma unroll
                for (int k = 0; k < 5; k++) v3[k] = r3[k];
                if ((int)k0 != curKey) { FLUSH_ACC(); curKey = (int)k0; ZERO_ACC(); }
                ACCUM(v0);
                if ((int)k1 != curKey) { FLUSH_ACC(); curKey = (int)k1; ZERO_ACC(); }
                ACCUM(v1);
                if ((int)k2 != curKey) { FLUSH_ACC(); curKey = (int)k2; ZERO_ACC(); }
                ACCUM(v2);
                if ((int)k3 != curKey) { FLUSH_ACC(); curKey = (int)k3; ZERO_ACC(); }
                ACCUM(v3);
            }
            for (; i < i1; i++) {
                unsigned p0 = sbuf[i];
                unsigned k0 = p0 & KM;
                const float2* r0 = (const float2*)(fsrc + (size_t)(rbase[k0] + (p0 >> KSH)) * F);
                float2 v0[5];
#pragma unroll
                for (int k = 0; k < 5; k++) v0[k] = r0[k];
                if ((int)k0 != curKey) { FLUSH_ACC(); curKey = (int)k0; ZERO_ACC(); }
                ACCUM(v0);
            }
            FLUSH_ACC();
#undef FLUSH_ACC
#undef ZERO_ACC
#undef ACCUM
        }
    } else {
        // overflow fallback (statistically unreachable): per-edge atomics
        for (unsigned e = lo + tid; e < hi; e += BSZ) {
            unsigned pay = sorted[e];
            unsigned l = pay & KM, s = pay >> KSH;
            const float2* row = (const float2*)(fsrc + (size_t)(rbase[l] + s) * F);
            float* a = acc + l * ASTR;
#pragma unroll
            for (int k = 0; k < 5; k++) {
                float2 v = row[k];
                atomicAdd(a + 2 * k, v.x);
                atomicAdd(a + 2 * k + 1, v.y);
            }
            atomicAdd(&hist[l], 1u);
        }
    }
    __syncthreads();

    // epilogue: fused projection
    const float* fdst = isU ? fdst_u : fdst_i;
    const float* wsf = isU ? wsf_u : wsf_i;
    const float* wnf = isU ? wnf_u : wnf_i;
    const float* bia = isU ? bia_u : bia_i;
    float* out = isU ? out_u : out_i;

    int tot = (int)NKEY * D;
    for (int o = tid; o < tot; o += BSZ) {
        int local = o / D, d = o - local * D;
        unsigned key = keybase + (unsigned)local;
        if (key >= (unsigned)(R)*N) continue;
        unsigned r = key / N, n = key - r * N;
        float inv = 1.f / fmaxf((float)hist[local], 1.f);
        const float* fd = fdst + ((size_t)r * N + n) * F;
        const float* a = acc + local * ASTR;
        const float* wsp = wsf + (size_t)r * F * D + d;
        const float* wnp = wnf + (size_t)r * F * D + d;
        float o1 = bia[r * D + d], o2 = 0.f;
#pragma unroll
        for (int f = 0; f < F; f++) {
            o1 += fd[f] * wsp[(size_t)f * D];
            o2 += a[f] * wnp[(size_t)f * D];
        }
        out[(size_t)n * (R * D) + r * D + d] = o1 + o2 * inv;
    }
}

// ======================= round-1 fallback (small ws) =======================
#define SUM_I_OFF 0
#define CNT_I_OFF ((size_t)R * M * F)
#define SUM_U_OFF (CNT_I_OFF + (size_t)R * M)
#define CNT_U_OFF (SUM_U_OFF + (size_t)R * U * F)
#define WS_FLOATS (CNT_U_OFF + (size_t)R * U)

__global__ void scatter_edges(const int* __restrict__ esrc, const int* __restrict__ edst,
                              const float* __restrict__ feat_u_fwd,
                              const float* __restrict__ feat_i_rev, float* __restrict__ ws) {
    float* sum_i = ws + SUM_I_OFF;
    float* cnt_i = ws + CNT_I_OFF;
    float* sum_u = ws + SUM_U_OFF;
    float* cnt_u = ws + CNT_U_OFF;
    const int total = R * E;
    for (int idx = blockIdx.x * blockDim.x + threadIdx.x; idx < total;
         idx += gridDim.x * blockDim.x) {
        int r = idx / E;
        int s = esrc[idx], d = edst[idx];
        const float* fu = feat_u_fwd + ((size_t)r * U + s) * F;
        const float* fi = feat_i_rev + ((size_t)r * M + d) * F;
        float* si = sum_i + ((size_t)r * M + d) * F;
        float* su = sum_u + ((size_t)r * U + s) * F;
#pragma unroll
        for (int f = 0; f < F; ++f) {
            atomicAdd(si + f, fu[f]);
            atomicAdd(su + f, fi[f]);
        }
        atomicAdd(cnt_i + (size_t)r * M + d, 1.0f);
        atomicAdd(cnt_u + (size_t)r * U + s, 1.0f);
    }
}

__global__ void finalize_nodes(int N, const float* __restrict__ feat_dst,
                               const float* __restrict__ w_self, const float* __restrict__ w_neigh,
                               const float* __restrict__ bias, const float* __restrict__ sum,
                               const float* __restrict__ cnt, float* __restrict__ out) {
    int idx = blockIdx.x * blockDim.x + threadIdx.x;
    int total = N * R * D;
    if (idx >= total) return;
    int n = idx / (R * D);
    int rd = idx - n * (R * D);
    int r = rd / D;
    int d = rd - r * D;
    const float* fd = feat_dst + ((size_t)r * N + n) * F;
    const float* sn = sum + ((size_t)r * N + n) * F;
    float inv = 1.0f / fmaxf(cnt[(size_t)r * N + n], 1.0f);
    const float* wsp = w_self + (size_t)r * F * D + d;
    const float* wnp = w_neigh + (size_t)r * F * D + d;
    float acc_self = bias[r * D + d];
    float acc_n = 0.0f;
#pragma unroll
    for (int f = 0; f < F; ++f) {
        acc_self += fd[f] * wsp[(size_t)f * D];
        acc_n += sn[f] * wnp[(size_t)f * D];
    }
    out[idx] = acc_self + acc_n * inv;
}

// ======================= launch =======================
extern "C" void kernel_launch(void* const* d_in, const int* in_sizes, int n_in,
                              void* d_out, int out_size, void* d_ws, size_t ws_size,
                              hipStream_t stream) {
    const int* edges_src = (const int*)d_in[0];
    const int* edges_dst = (const int*)d_in[1];
    const float* feat_u_fwd = (const float*)d_in[2];
    const float* feat_i_fwd = (const float*)d_in[3];
    const float* feat_i_rev = (const float*)d_in[4];
    const float* feat_u_rev = (const float*)d_in[5];
    const float* w_self_fwd = (const float*)d_in[6];
    const float* w_neigh_fwd = (const float*)d_in[7];
    const float* b_fwd = (const float*)d_in[8];
    const float* w_self_rev = (const float*)d_in[9];
    const float* w_neigh_rev = (const float*)d_in[10];
    const float* b_rev = (const float*)d_in[11];

    float* out = (float*)d_out;
    float* out_u = out;
    float* out_i = out + (size_t)U * R * D;

    // sorted (2*TE) + S/ghist in-place (GTOT) + psum (2048)  ~= 86.0 MB
    size_t need = ((size_t)2 * TE + (size_t)GTOT + 2048ull) * 4ull;
    if (ws_size >= need) {
        unsigned* sorted = (unsigned*)d_ws;
        unsigned* S = sorted + (size_t)2 * TE;
        unsigned* psum = S + GTOT;

        phaseA<<<NBLK, BSZ, 0, stream>>>(edges_src, edges_dst, S);
        scan1<<<NS1, BSZ, 0, stream>>>(S, psum);
        scan2<<<1, BSZ, 0, stream>>>(psum);
        scan3<<<NS1, BSZ, 0, stream>>>(S, psum);
        phaseC<<<NBLK, BSZ, 0, stream>>>(edges_src, edges_dst, S, sorted);
        phaseD<<<NBU_T, BSZ, 0, stream>>>(sorted, S,
                                          feat_i_rev, feat_u_rev, w_self_rev, w_neigh_rev, b_rev,
                                          feat_u_fwd, feat_i_fwd, w_self_fwd, w_neigh_fwd, b_fwd,
                                          out_u, out_i);
    } else {
        // fallback: round-1 global-atomic path
        float* ws = (float*)d_ws;
        hipMemsetAsync(d_ws, 0, WS_FLOATS * sizeof(float), stream);
        scatter_edges<<<4096, 256, 0, stream>>>(edges_src, edges_dst, feat_u_fwd, feat_i_rev, ws);
        finalize_nodes<<<(U * R * D + 255) / 256, 256, 0, stream>>>(
            U, feat_u_rev, w_self_rev, w_neigh_rev, b_rev, ws + SUM_U_OFF, ws + CNT_U_OFF, out_u);
        finalize_nodes<<<(M * R * D + 255) / 256, 256, 0, stream>>>(
            M, feat_i_fwd, w_self_fwd, w_neigh_fwd, b_fwd, ws + SUM_I_OFF, ws + CNT_I_OFF, out_i);
    }
}

// Round 16
// 737.904 us; speedup vs baseline: 1.2953x; 1.0194x over previous
//
#include <hip/hip_runtime.h>

#define R 5
#define U 100000
#define M 50000
#define E 2000000
#define F 10
#define D 50

#define TE (R * E)                      // 10,000,000 edges per direction
#define NBLK 192                        // phase A/C block count (ws fits 86MB)
#define CHUNK ((TE + NBLK - 1) / NBLK)  // 52,084 edges per block
#define BSZ 256

// balanced buckets: user avg degree 20, item avg degree 40 -> equal edges/bucket
#define NKEY_U 128
#define NKEY_I 64
#define KS_U (R * U)
#define KS_I (R * M)
#define NBU_U ((KS_U + NKEY_U - 1) / NKEY_U)  // 3907
#define NBU_I ((KS_I + NKEY_I - 1) / NKEY_I)  // 3907
#define NBU_T (NBU_U + NBU_I)                 // 7814
#define OFFI (NBU_U * NBLK)
#define GTOT (OFFI + NBU_I * NBLK)            // 1,500,288
#define NS1 ((GTOT + 1023) / 1024)
#define S2K ((NS1 + 255) / 256)

#define CAP 3328                        // max edges/bucket (mean 2560 + 15 sigma)
#define ASTR 11                         // acc stride (gcd(11,32)=1)

// ======================= bucketed counting-sort path =======================

__global__ __launch_bounds__(BSZ) void phaseA(const int* __restrict__ esrc,
                                              const int* __restrict__ edst,
                                              unsigned* __restrict__ ghist) {
    __shared__ unsigned hist[NBU_T];
    for (int i = threadIdx.x; i < NBU_T; i += BSZ) hist[i] = 0;
    __syncthreads();
    int b = blockIdx.x;
    int lo = b * CHUNK, hi = min(lo + CHUNK, TE);
    for (int i = lo + threadIdx.x; i < hi; i += BSZ) {
        unsigned r = (unsigned)i / (unsigned)E;
        int s = esrc[i], d = edst[i];
        unsigned ku = r * U + (unsigned)s;
        unsigned ki = r * M + (unsigned)d;
        atomicAdd(&hist[ku >> 7], 1u);
        atomicAdd(&hist[NBU_U + (ki >> 6)], 1u);
    }
    __syncthreads();
    for (int j = threadIdx.x; j < NBU_T; j += BSZ) {
        unsigned idx = (j < NBU_U) ? (unsigned)j * NBLK + b
                                   : OFFI + (unsigned)(j - NBU_U) * NBLK + b;
        ghist[idx] = hist[j];
    }
}

__global__ __launch_bounds__(BSZ) void scan1(unsigned* __restrict__ S,
                                             unsigned* __restrict__ psum) {
    __shared__ unsigned sh[BSZ];
    int base = blockIdx.x * 1024 + threadIdx.x * 4;
    unsigned v[4], tsum = 0;
    for (int k = 0; k < 4; k++) {
        int i = base + k;
        v[k] = (i < GTOT) ? S[i] : 0u;
        tsum += v[k];
    }
    sh[threadIdx.x] = tsum;
    __syncthreads();
    for (int off = 1; off < BSZ; off <<= 1) {
        unsigned t = (threadIdx.x >= off) ? sh[threadIdx.x - off] : 0u;
        __syncthreads();
        sh[threadIdx.x] += t;
        __syncthreads();
    }
    unsigned ex = sh[threadIdx.x] - tsum;
    for (int k = 0; k < 4; k++) {
        int i = base + k;
        if (i < GTOT) S[i] = ex;
        ex += v[k];
    }
    if (threadIdx.x == BSZ - 1) psum[blockIdx.x] = sh[BSZ - 1];
}

__global__ __launch_bounds__(BSZ) void scan2(unsigned* __restrict__ psum) {
    __shared__ unsigned sh[BSZ];
    unsigned v[S2K], tsum = 0;
    int base = threadIdx.x * S2K;
    for (int k = 0; k < S2K; k++) {
        int i = base + k;
        v[k] = (i < NS1) ? psum[i] : 0u;
        tsum += v[k];
    }
    sh[threadIdx.x] = tsum;
    __syncthreads();
    for (int off = 1; off < BSZ; off <<= 1) {
        unsigned t = (threadIdx.x >= off) ? sh[threadIdx.x - off] : 0u;
        __syncthreads();
        sh[threadIdx.x] += t;
        __syncthreads();
    }
    unsigned ex = sh[threadIdx.x] - tsum;
    for (int k = 0; k < S2K; k++) {
        int i = base + k;
        if (i < NS1) psum[i] = ex;
        ex += v[k];
    }
}

__global__ __launch_bounds__(BSZ) void scan3(unsigned* __restrict__ S,
                                             const unsigned* __restrict__ psum) {
    unsigned add = psum[blockIdx.x];
    int base = blockIdx.x * 1024 + threadIdx.x * 4;
    for (int k = 0; k < 4; k++) {
        int i = base + k;
        if (i < GTOT) S[i] += add;
    }
}

// user payload = local(7b) | item_id<<7 ; item payload = local(6b) | user_id<<6
__global__ __launch_bounds__(BSZ) void phaseC(const int* __restrict__ esrc,
                                              const int* __restrict__ edst,
                                              const unsigned* __restrict__ S,
                                              unsigned* __restrict__ sorted) {
    __shared__ unsigned cur[NBU_T];
    int b = blockIdx.x;
    for (int j = threadIdx.x; j < NBU_T; j += BSZ) {
        unsigned idx = (j < NBU_U) ? (unsigned)j * NBLK + b
                                   : OFFI + (unsigned)(j - NBU_U) * NBLK + b;
        cur[j] = S[idx];
    }
    __syncthreads();
    int lo = b * CHUNK, hi = min(lo + CHUNK, TE);
    for (int i = lo + threadIdx.x; i < hi; i += BSZ) {
        unsigned r = (unsigned)i / (unsigned)E;
        int s = esrc[i], d = edst[i];
        unsigned ku = r * U + (unsigned)s;
        unsigned ki = r * M + (unsigned)d;
        unsigned pu = atomicAdd(&cur[ku >> 7], 1u);
        sorted[pu] = (ku & 127u) | ((unsigned)d << 7);
        unsigned pi = atomicAdd(&cur[NBU_U + (ki >> 6)], 1u);
        sorted[pi] = (ki & 63u) | ((unsigned)s << 6);
    }
}

// phaseD v7: v5 structure, but step 4 with COMPILED-IN 4-deep gather ILP:
// __launch_bounds__(BSZ,4) raises the VGPR cap to 128 so the compiler can
// keep all 20 float2 loads in flight (v6 at cap-64 chose 32 VGPRs and
// serialized them -- observable: VGPR_Count stayed 32). Verification signal
// for this round: VGPR_Count should jump to ~80-110.
__global__ __launch_bounds__(BSZ, 4) void phaseD(
    const unsigned* __restrict__ sorted, const unsigned* __restrict__ S,
    const float* __restrict__ fsrc_u, const float* __restrict__ fdst_u,
    const float* __restrict__ wsf_u, const float* __restrict__ wnf_u,
    const float* __restrict__ bia_u,
    const float* __restrict__ fsrc_i, const float* __restrict__ fdst_i,
    const float* __restrict__ wsf_i, const float* __restrict__ wnf_i,
    const float* __restrict__ bia_i,
    float* __restrict__ out_u, float* __restrict__ out_i) {
    __shared__ unsigned sbuf[CAP];
    __shared__ float acc[NKEY_U * ASTR];
    __shared__ unsigned hist[NKEY_U];
    __shared__ unsigned cur[NKEY_U];
    __shared__ unsigned rbase[NKEY_U];

    // per-direction bijective XCD swizzle (NBU_U == NBU_I == 3907)
    unsigned orig = blockIdx.x;
    unsigned bkt;
    {
        unsigned o = (orig < NBU_U) ? orig : orig - NBU_U;
        const unsigned q = NBU_U / 8u, rem = NBU_U % 8u;
        unsigned x = o & 7u, off = o >> 3;
        unsigned m = (x < rem ? x * (q + 1u) : rem * (q + 1u) + (x - rem) * q) + off;
        bkt = (orig < NBU_U) ? m : NBU_U + m;
    }

    bool isU = bkt < NBU_U;
    int j = isU ? (int)bkt : (int)bkt - NBU_U;
    unsigned N = isU ? U : M;
    unsigned NSRC = isU ? M : U;
    unsigned NKEY = isU ? NKEY_U : NKEY_I;
    unsigned KM = NKEY - 1u;
    unsigned KSH = isU ? 7u : 6u;
    const float* fsrc = isU ? fsrc_u : fsrc_i;

    unsigned sbase = isU ? 0u : (unsigned)OFFI;
    unsigned lo = S[sbase + (unsigned)j * NBLK];
    unsigned hi = (!isU && j + 1 == NBU_I) ? (unsigned)(2 * TE)
                                           : S[sbase + (unsigned)(j + 1) * NBLK];
    unsigned len = hi - lo;
    unsigned keybase = (unsigned)j * NKEY;
    int tid = threadIdx.x;

    for (int t = tid; t < NKEY_U * ASTR; t += BSZ) acc[t] = 0.f;
    if (tid < NKEY_U) {
        hist[tid] = 0u;
        unsigned key = keybase + (unsigned)tid;
        unsigned r = (key < (unsigned)R * N) ? key / N : 0u;
        rbase[tid] = r * NSRC;
    }
    __syncthreads();

    if (len <= CAP) {
        // step 1: per-key histogram
        for (unsigned e = lo + tid; e < hi; e += BSZ)
            atomicAdd(&hist[sorted[e] & KM], 1u);
        __syncthreads();
        // step 2: exclusive scan of hist -> cur
        if (tid < NKEY) cur[tid] = hist[tid];
        __syncthreads();
        for (int off = 1; off < (int)NKEY; off <<= 1) {
            unsigned t = 0;
            if (tid < (int)NKEY && tid >= off) t = cur[tid - off];
            __syncthreads();
            if (tid < (int)NKEY && tid >= off) cur[tid] += t;
            __syncthreads();
        }
        if (tid < (int)NKEY) cur[tid] -= hist[tid];
        __syncthreads();
        // step 3: key-sort into LDS
        for (unsigned e = lo + tid; e < hi; e += BSZ) {
            unsigned pay = sorted[e];
            unsigned pos = atomicAdd(&cur[pay & KM], 1u);
            sbuf[pos] = pay;
        }
        __syncthreads();
        // step 4: register segmented reduce, true 4-deep gather pipeline
        unsigned L = (len + BSZ - 1) / BSZ;
        unsigned i0 = (unsigned)tid * L;
        unsigned i1 = min(i0 + L, len);
        if (i0 < i1) {
            int curKey = -1;
            float A0 = 0, A1 = 0, A2 = 0, A3 = 0, A4 = 0,
                  A5 = 0, A6 = 0, A7 = 0, A8 = 0, A9 = 0;
#define FLUSH_ACC()                                                        \
    do {                                                                   \
        if (curKey >= 0) {                                                 \
            float* ap = acc + curKey * ASTR;                               \
            atomicAdd(ap + 0, A0); atomicAdd(ap + 1, A1);                  \
            atomicAdd(ap + 2, A2); atomicAdd(ap + 3, A3);                  \
            atomicAdd(ap + 4, A4); atomicAdd(ap + 5, A5);                  \
            atomicAdd(ap + 6, A6); atomicAdd(ap + 7, A7);                  \
            atomicAdd(ap + 8, A8); atomicAdd(ap + 9, A9);                  \
        }                                                                  \
    } while (0)
#define ZERO_ACC() A0=A1=A2=A3=A4=A5=A6=A7=A8=A9=0.f
#define ACC10(a0,a1,a2,a3,a4)                                              \
    do {                                                                   \
        A0 += (a0).x; A1 += (a0).y; A2 += (a1).x; A3 += (a1).y;            \
        A4 += (a2).x; A5 += (a2).y; A6 += (a3).x; A7 += (a3).y;            \
        A8 += (a4).x; A9 += (a4).y;                                        \
    } while (0)
            unsigned i = i0;
            for (; i + 3 < i1; i += 4) {
                unsigned p0 = sbuf[i], p1 = sbuf[i + 1];
                unsigned p2 = sbuf[i + 2], p3 = sbuf[i + 3];
                unsigned k0 = p0 & KM, k1 = p1 & KM, k2 = p2 & KM, k3 = p3 & KM;
                const float2* r0 = (const float2*)(fsrc + (size_t)(rbase[k0] + (p0 >> KSH)) * F);
                const float2* r1 = (const float2*)(fsrc + (size_t)(rbase[k1] + (p1 >> KSH)) * F);
                const float2* r2 = (const float2*)(fsrc + (size_t)(rbase[k2] + (p2 >> KSH)) * F);
                const float2* r3 = (const float2*)(fsrc + (size_t)(rbase[k3] + (p3 >> KSH)) * F);
                // all 20 loads issued before any use; 128-VGPR budget keeps them live
                float2 a0 = r0[0], a1 = r0[1], a2 = r0[2], a3 = r0[3], a4 = r0[4];
                float2 b0 = r1[0], b1 = r1[1], b2 = r1[2], b3 = r1[3], b4 = r1[4];
                float2 c0 = r2[0], c1 = r2[1], c2 = r2[2], c3 = r2[3], c4 = r2[4];
                float2 d0 = r3[0], d1 = r3[1], d2 = r3[2], d3 = r3[3], d4 = r3[4];
                if ((int)k0 != curKey) { FLUSH_ACC(); curKey = (int)k0; ZERO_ACC(); }
                ACC10(a0, a1, a2, a3, a4);
                if ((int)k1 != curKey) { FLUSH_ACC(); curKey = (int)k1; ZERO_ACC(); }
                ACC10(b0, b1, b2, b3, b4);
                if ((int)k2 != curKey) { FLUSH_ACC(); curKey = (int)k2; ZERO_ACC(); }
                ACC10(c0, c1, c2, c3, c4);
                if ((int)k3 != curKey) { FLUSH_ACC(); curKey = (int)k3; ZERO_ACC(); }
                ACC10(d0, d1, d2, d3, d4);
            }
            for (; i < i1; i++) {
                unsigned p0 = sbuf[i];
                unsigned k0 = p0 & KM;
                const float2* r0 = (const float2*)(fsrc + (size_t)(rbase[k0] + (p0 >> KSH)) * F);
                float2 a0 = r0[0], a1 = r0[1], a2 = r0[2], a3 = r0[3], a4 = r0[4];
                if ((int)k0 != curKey) { FLUSH_ACC(); curKey = (int)k0; ZERO_ACC(); }
                ACC10(a0, a1, a2, a3, a4);
            }
            FLUSH_ACC();
#undef FLUSH_ACC
#undef ZERO_ACC
#undef ACC10
        }
    } else {
        // overflow fallback (statistically unreachable): per-edge atomics
        for (unsigned e = lo + tid; e < hi; e += BSZ) {
            unsigned pay = sorted[e];
            unsigned l = pay & KM, s = pay >> KSH;
            const float2* row = (const float2*)(fsrc + (size_t)(rbase[l] + s) * F);
            float* a = acc + l * ASTR;
#pragma unroll
            for (int k = 0; k < 5; k++) {
                float2 v = row[k];
                atomicAdd(a + 2 * k, v.x);
                atomicAdd(a + 2 * k + 1, v.y);
            }
            atomicAdd(&hist[l], 1u);
        }
    }
    __syncthreads();

    // epilogue: fused projection
    const float* fdst = isU ? fdst_u : fdst_i;
    const float* wsf = isU ? wsf_u : wsf_i;
    const float* wnf = isU ? wnf_u : wnf_i;
    const float* bia = isU ? bia_u : bia_i;
    float* out = isU ? out_u : out_i;

    int tot = (int)NKEY * D;
    for (int o = tid; o < tot; o += BSZ) {
        int local = o / D, d = o - local * D;
        unsigned key = keybase + (unsigned)local;
        if (key >= (unsigned)(R)*N) continue;
        unsigned r = key / N, n = key - r * N;
        float inv = 1.f / fmaxf((float)hist[local], 1.f);
        const float* fd = fdst + ((size_t)r * N + n) * F;
        const float* a = acc + local * ASTR;
        const float* wsp = wsf + (size_t)r * F * D + d;
        const float* wnp = wnf + (size_t)r * F * D + d;
        float o1 = bia[r * D + d], o2 = 0.f;
#pragma unroll
        for (int f = 0; f < F; f++) {
            o1 += fd[f] * wsp[(size_t)f * D];
            o2 += a[f] * wnp[(size_t)f * D];
        }
        out[(size_t)n * (R * D) + r * D + d] = o1 + o2 * inv;
    }
}

// ======================= round-1 fallback (small ws) =======================
#define SUM_I_OFF 0
#define CNT_I_OFF ((size_t)R * M * F)
#define SUM_U_OFF (CNT_I_OFF + (size_t)R * M)
#define CNT_U_OFF (SUM_U_OFF + (size_t)R * U * F)
#define WS_FLOATS (CNT_U_OFF + (size_t)R * U)

__global__ void scatter_edges(const int* __restrict__ esrc, const int* __restrict__ edst,
                              const float* __restrict__ feat_u_fwd,
                              const float* __restrict__ feat_i_rev, float* __restrict__ ws) {
    float* sum_i = ws + SUM_I_OFF;
    float* cnt_i = ws + CNT_I_OFF;
    float* sum_u = ws + SUM_U_OFF;
    float* cnt_u = ws + CNT_U_OFF;
    const int total = R * E;
    for (int idx = blockIdx.x * blockDim.x + threadIdx.x; idx < total;
         idx += gridDim.x * blockDim.x) {
        int r = idx / E;
        int s = esrc[idx], d = edst[idx];
        const float* fu = feat_u_fwd + ((size_t)r * U + s) * F;
        const float* fi = feat_i_rev + ((size_t)r * M + d) * F;
        float* si = sum_i + ((size_t)r * M + d) * F;
        float* su = sum_u + ((size_t)r * U + s) * F;
#pragma unroll
        for (int f = 0; f < F; ++f) {
            atomicAdd(si + f, fu[f]);
            atomicAdd(su + f, fi[f]);
        }
        atomicAdd(cnt_i + (size_t)r * M + d, 1.0f);
        atomicAdd(cnt_u + (size_t)r * U + s, 1.0f);
    }
}

__global__ void finalize_nodes(int N, const float* __restrict__ feat_dst,
                               const float* __restrict__ w_self, const float* __restrict__ w_neigh,
                               const float* __restrict__ bias, const float* __restrict__ sum,
                               const float* __restrict__ cnt, float* __restrict__ out) {
    int idx = blockIdx.x * blockDim.x + threadIdx.x;
    int total = N * R * D;
    if (idx >= total) return;
    int n = idx / (R * D);
    int rd = idx - n * (R * D);
    int r = rd / D;
    int d = rd - r * D;
    const float* fd = feat_dst + ((size_t)r * N + n) * F;
    const float* sn = sum + ((size_t)r * N + n) * F;
    float inv = 1.0f / fmaxf(cnt[(size_t)r * N + n], 1.0f);
    const float* wsp = w_self + (size_t)r * F * D + d;
    const float* wnp = w_neigh + (size_t)r * F * D + d;
    float acc_self = bias[r * D + d];
    float acc_n = 0.0f;
#pragma unroll
    for (int f = 0; f < F; ++f) {
        acc_self += fd[f] * wsp[(size_t)f * D];
        acc_n += sn[f] * wnp[(size_t)f * D];
    }
    out[idx] = acc_self + acc_n * inv;
}

// ======================= launch =======================
extern "C" void kernel_launch(void* const* d_in, const int* in_sizes, int n_in,
                              void* d_out, int out_size, void* d_ws, size_t ws_size,
                              hipStream_t stream) {
    const int* edges_src = (const int*)d_in[0];
    const int* edges_dst = (const int*)d_in[1];
    const float* feat_u_fwd = (const float*)d_in[2];
    const float* feat_i_fwd = (const float*)d_in[3];
    const float* feat_i_rev = (const float*)d_in[4];
    const float* feat_u_rev = (const float*)d_in[5];
    const float* w_self_fwd = (const float*)d_in[6];
    const float* w_neigh_fwd = (const float*)d_in[7];
    const float* b_fwd = (const float*)d_in[8];
    const float* w_self_rev = (const float*)d_in[9];
    const float* w_neigh_rev = (const float*)d_in[10];
    const float* b_rev = (const float*)d_in[11];

    float* out = (float*)d_out;
    float* out_u = out;
    float* out_i = out + (size_t)U * R * D;

    // sorted (2*TE) + S/ghist in-place (GTOT) + psum (2048)  ~= 86.0 MB
    size_t need = ((size_t)2 * TE + (size_t)GTOT + 2048ull) * 4ull;
    if (ws_size >= need) {
        unsigned* sorted = (unsigned*)d_ws;
        unsigned* S = sorted + (size_t)2 * TE;
        unsigned* psum = S + GTOT;

        phaseA<<<NBLK, BSZ, 0, stream>>>(edges_src, edges_dst, S);
        scan1<<<NS1, BSZ, 0, stream>>>(S, psum);
        scan2<<<1, BSZ, 0, stream>>>(psum);
        scan3<<<NS1, BSZ, 0, stream>>>(S, psum);
        phaseC<<<NBLK, BSZ, 0, stream>>>(edges_src, edges_dst, S, sorted);
        phaseD<<<NBU_T, BSZ, 0, stream>>>(sorted, S,
                                          feat_i_rev, feat_u_rev, w_self_rev, w_neigh_rev, b_rev,
                                          feat_u_fwd, feat_i_fwd, w_self_fwd, w_neigh_fwd, b_fwd,
                                          out_u, out_i);
    } else {
        // fallback: round-1 global-atomic path
        float* ws = (float*)d_ws;
        hipMemsetAsync(d_ws, 0, WS_FLOATS * sizeof(float), stream);
        scatter_edges<<<4096, 256, 0, stream>>>(edges_src, edges_dst, feat_u_fwd, feat_i_rev, ws);
        finalize_nodes<<<(U * R * D + 255) / 256, 256, 0, stream>>>(
            U, feat_u_rev, w_self_rev, w_neigh_rev, b_rev, ws + SUM_U_OFF, ws + CNT_U_OFF, out_u);
        finalize_nodes<<<(M * R * D + 255) / 256, 256, 0, stream>>>(
            M, feat_i_fwd, w_self_fwd, w_neigh_fwd, b_fwd, ws + SUM_I_OFF, ws + CNT_I_OFF, out_i);
    }
}

// Round 18
// 650.809 us; speedup vs baseline: 1.4687x; 1.1338x over previous
//
#include <hip/hip_runtime.h>

#define R 5
#define U 100000
#define M 50000
#define E 2000000
#define F 10
#define D 50

#define TE (R * E)                      // 10,000,000 edges per direction
#define NBLK 192                        // chunk count (ws layout, proven 86MB)
#define CHUNK ((TE + NBLK - 1) / NBLK)  // 52,084 edges per chunk
#define BSZ 256                         // phaseD block size
#define BSZ_AC 1024                     // phaseA/C block size (more waves/CU)

// balanced buckets: user avg degree 20, item avg degree 40 -> equal edges/bucket
#define NKEY_U 128
#define NKEY_I 64
#define KS_U (R * U)
#define KS_I (R * M)
#define NBU_U ((KS_U + NKEY_U - 1) / NKEY_U)  // 3907
#define NBU_I ((KS_I + NKEY_I - 1) / NKEY_I)  // 3907
#define NBU_T (NBU_U + NBU_I)                 // 7814
#define OFFI (NBU_U * NBLK)
#define GTOT (OFFI + NBU_I * NBLK)            // 1,500,288
#define NS1 ((GTOT + 1023) / 1024)
#define S2K ((NS1 + 255) / 256)

#define CAP 3328                        // max edges/bucket (mean 2560 + 15 sigma)
#define ASTR 11                         // acc stride (gcd(11,32)=1)

// ======================= bucketed counting-sort path =======================

// A/C at 1024 threads: same 192 chunks, 4x waves per CU for latency hiding.
__global__ __launch_bounds__(BSZ_AC) void phaseA(const int* __restrict__ esrc,
                                                 const int* __restrict__ edst,
                                                 unsigned* __restrict__ ghist) {
    __shared__ unsigned hist[NBU_T];
    for (int i = threadIdx.x; i < NBU_T; i += BSZ_AC) hist[i] = 0;
    __syncthreads();
    int b = blockIdx.x;
    int lo = b * CHUNK, hi = min(lo + CHUNK, TE);
    for (int i = lo + threadIdx.x; i < hi; i += BSZ_AC) {
        unsigned r = (unsigned)i / (unsigned)E;
        int s = esrc[i], d = edst[i];
        unsigned ku = r * U + (unsigned)s;
        unsigned ki = r * M + (unsigned)d;
        atomicAdd(&hist[ku >> 7], 1u);
        atomicAdd(&hist[NBU_U + (ki >> 6)], 1u);
    }
    __syncthreads();
    for (int j = threadIdx.x; j < NBU_T; j += BSZ_AC) {
        unsigned idx = (j < NBU_U) ? (unsigned)j * NBLK + b
                                   : OFFI + (unsigned)(j - NBU_U) * NBLK + b;
        ghist[idx] = hist[j];
    }
}

__global__ __launch_bounds__(BSZ) void scan1(unsigned* __restrict__ S,
                                             unsigned* __restrict__ psum) {
    __shared__ unsigned sh[BSZ];
    int base = blockIdx.x * 1024 + threadIdx.x * 4;
    unsigned v[4], tsum = 0;
    for (int k = 0; k < 4; k++) {
        int i = base + k;
        v[k] = (i < GTOT) ? S[i] : 0u;
        tsum += v[k];
    }
    sh[threadIdx.x] = tsum;
    __syncthreads();
    for (int off = 1; off < BSZ; off <<= 1) {
        unsigned t = (threadIdx.x >= off) ? sh[threadIdx.x - off] : 0u;
        __syncthreads();
        sh[threadIdx.x] += t;
        __syncthreads();
    }
    unsigned ex = sh[threadIdx.x] - tsum;
    for (int k = 0; k < 4; k++) {
        int i = base + k;
        if (i < GTOT) S[i] = ex;
        ex += v[k];
    }
    if (threadIdx.x == BSZ - 1) psum[blockIdx.x] = sh[BSZ - 1];
}

__global__ __launch_bounds__(BSZ) void scan2(unsigned* __restrict__ psum) {
    __shared__ unsigned sh[BSZ];
    unsigned v[S2K], tsum = 0;
    int base = threadIdx.x * S2K;
    for (int k = 0; k < S2K; k++) {
        int i = base + k;
        v[k] = (i < NS1) ? psum[i] : 0u;
        tsum += v[k];
    }
    sh[threadIdx.x] = tsum;
    __syncthreads();
    for (int off = 1; off < BSZ; off <<= 1) {
        unsigned t = (threadIdx.x >= off) ? sh[threadIdx.x - off] : 0u;
        __syncthreads();
        sh[threadIdx.x] += t;
        __syncthreads();
    }
    unsigned ex = sh[threadIdx.x] - tsum;
    for (int k = 0; k < S2K; k++) {
        int i = base + k;
        if (i < NS1) psum[i] = ex;
        ex += v[k];
    }
}

__global__ __launch_bounds__(BSZ) void scan3(unsigned* __restrict__ S,
                                             const unsigned* __restrict__ psum) {
    unsigned add = psum[blockIdx.x];
    int base = blockIdx.x * 1024 + threadIdx.x * 4;
    for (int k = 0; k < 4; k++) {
        int i = base + k;
        if (i < GTOT) S[i] += add;
    }
}

// user payload = local(7b) | item_id<<7 ; item payload = local(6b) | user_id<<6
__global__ __launch_bounds__(BSZ_AC) void phaseC(const int* __restrict__ esrc,
                                                 const int* __restrict__ edst,
                                                 const unsigned* __restrict__ S,
                                                 unsigned* __restrict__ sorted) {
    __shared__ unsigned cur[NBU_T];
    int b = blockIdx.x;
    for (int j = threadIdx.x; j < NBU_T; j += BSZ_AC) {
        unsigned idx = (j < NBU_U) ? (unsigned)j * NBLK + b
                                   : OFFI + (unsigned)(j - NBU_U) * NBLK + b;
        cur[j] = S[idx];
    }
    __syncthreads();
    int lo = b * CHUNK, hi = min(lo + CHUNK, TE);
    for (int i = lo + threadIdx.x; i < hi; i += BSZ_AC) {
        unsigned r = (unsigned)i / (unsigned)E;
        int s = esrc[i], d = edst[i];
        unsigned ku = r * U + (unsigned)s;
        unsigned ki = r * M + (unsigned)d;
        unsigned pu = atomicAdd(&cur[ku >> 7], 1u);
        sorted[pu] = (ku & 127u) | ((unsigned)d << 7);
        unsigned pi = atomicAdd(&cur[NBU_U + (ki >> 6)], 1u);
        sorted[pi] = (ki & 63u) | ((unsigned)s << 6);
    }
}

// phaseD: v5 structure (in-LDS counting sort + register segmented reduce).
// Established across rounds 11-16: flat at ~445-470us vs TLP/ILP/bytes -- at
// its VALU-issue + scattered-VMEM floor for this structure.
__global__ __launch_bounds__(BSZ, 4) void phaseD(
    const unsigned* __restrict__ sorted, const unsigned* __restrict__ S,
    const float* __restrict__ fsrc_u, const float* __restrict__ fdst_u,
    const float* __restrict__ wsf_u, const float* __restrict__ wnf_u,
    const float* __restrict__ bia_u,
    const float* __restrict__ fsrc_i, const float* __restrict__ fdst_i,
    const float* __restrict__ wsf_i, const float* __restrict__ wnf_i,
    const float* __restrict__ bia_i,
    float* __restrict__ out_u, float* __restrict__ out_i) {
    __shared__ unsigned sbuf[CAP];
    __shared__ float acc[NKEY_U * ASTR];
    __shared__ unsigned hist[NKEY_U];
    __shared__ unsigned cur[NKEY_U];
    __shared__ unsigned rbase[NKEY_U];

    // per-direction bijective XCD swizzle (NBU_U == NBU_I == 3907)
    unsigned orig = blockIdx.x;
    unsigned bkt;
    {
        unsigned o = (orig < NBU_U) ? orig : orig - NBU_U;
        const unsigned q = NBU_U / 8u, rem = NBU_U % 8u;
        unsigned x = o & 7u, off = o >> 3;
        unsigned m = (x < rem ? x * (q + 1u) : rem * (q + 1u) + (x - rem) * q) + off;
        bkt = (orig < NBU_U) ? m : NBU_U + m;
    }

    bool isU = bkt < NBU_U;
    int j = isU ? (int)bkt : (int)bkt - NBU_U;
    unsigned N = isU ? U : M;
    unsigned NSRC = isU ? M : U;
    unsigned NKEY = isU ? NKEY_U : NKEY_I;
    unsigned KM = NKEY - 1u;
    unsigned KSH = isU ? 7u : 6u;
    const float* fsrc = isU ? fsrc_u : fsrc_i;

    unsigned sbase = isU ? 0u : (unsigned)OFFI;
    unsigned lo = S[sbase + (unsigned)j * NBLK];
    unsigned hi = (!isU && j + 1 == NBU_I) ? (unsigned)(2 * TE)
                                           : S[sbase + (unsigned)(j + 1) * NBLK];
    unsigned len = hi - lo;
    unsigned keybase = (unsigned)j * NKEY;
    int tid = threadIdx.x;

    for (int t = tid; t < NKEY_U * ASTR; t += BSZ) acc[t] = 0.f;
    if (tid < NKEY_U) {
        hist[tid] = 0u;
        unsigned key = keybase + (unsigned)tid;
        unsigned r = (key < (unsigned)R * N) ? key / N : 0u;
        rbase[tid] = r * NSRC;
    }
    __syncthreads();

    if (len <= CAP) {
        // step 1: per-key histogram
        for (unsigned e = lo + tid; e < hi; e += BSZ)
            atomicAdd(&hist[sorted[e] & KM], 1u);
        __syncthreads();
        // step 2: exclusive scan of hist -> cur
        if (tid < NKEY) cur[tid] = hist[tid];
        __syncthreads();
        for (int off = 1; off < (int)NKEY; off <<= 1) {
            unsigned t = 0;
            if (tid < (int)NKEY && tid >= off) t = cur[tid - off];
            __syncthreads();
            if (tid < (int)NKEY && tid >= off) cur[tid] += t;
            __syncthreads();
        }
        if (tid < (int)NKEY) cur[tid] -= hist[tid];
        __syncthreads();
        // step 3: key-sort into LDS
        for (unsigned e = lo + tid; e < hi; e += BSZ) {
            unsigned pay = sorted[e];
            unsigned pos = atomicAdd(&cur[pay & KM], 1u);
            sbuf[pos] = pay;
        }
        __syncthreads();
        // step 4: register segmented reduce, 4-wide batch
        unsigned L = (len + BSZ - 1) / BSZ;
        unsigned i0 = (unsigned)tid * L;
        unsigned i1 = min(i0 + L, len);
        if (i0 < i1) {
            int curKey = -1;
            float A0 = 0, A1 = 0, A2 = 0, A3 = 0, A4 = 0,
                  A5 = 0, A6 = 0, A7 = 0, A8 = 0, A9 = 0;
#define FLUSH_ACC()                                                        \
    do {                                                                   \
        if (curKey >= 0) {                                                 \
            float* ap = acc + curKey * ASTR;                               \
            atomicAdd(ap + 0, A0); atomicAdd(ap + 1, A1);                  \
            atomicAdd(ap + 2, A2); atomicAdd(ap + 3, A3);                  \
            atomicAdd(ap + 4, A4); atomicAdd(ap + 5, A5);                  \
            atomicAdd(ap + 6, A6); atomicAdd(ap + 7, A7);                  \
            atomicAdd(ap + 8, A8); atomicAdd(ap + 9, A9);                  \
        }                                                                  \
    } while (0)
#define ZERO_ACC() A0=A1=A2=A3=A4=A5=A6=A7=A8=A9=0.f
#define ACC10(a0,a1,a2,a3,a4)                                              \
    do {                                                                   \
        A0 += (a0).x; A1 += (a0).y; A2 += (a1).x; A3 += (a1).y;            \
        A4 += (a2).x; A5 += (a2).y; A6 += (a3).x; A7 += (a3).y;            \
        A8 += (a4).x; A9 += (a4).y;                                        \
    } while (0)
            unsigned i = i0;
            for (; i + 3 < i1; i += 4) {
                unsigned p0 = sbuf[i], p1 = sbuf[i + 1];
                unsigned p2 = sbuf[i + 2], p3 = sbuf[i + 3];
                unsigned k0 = p0 & KM, k1 = p1 & KM, k2 = p2 & KM, k3 = p3 & KM;
                const float2* r0 = (const float2*)(fsrc + (size_t)(rbase[k0] + (p0 >> KSH)) * F);
                const float2* r1 = (const float2*)(fsrc + (size_t)(rbase[k1] + (p1 >> KSH)) * F);
                const float2* r2 = (const float2*)(fsrc + (size_t)(rbase[k2] + (p2 >> KSH)) * F);
                const float2* r3 = (const float2*)(fsrc + (size_t)(rbase[k3] + (p3 >> KSH)) * F);
                float2 a0 = r0[0], a1 = r0[1], a2 = r0[2], a3 = r0[3], a4 = r0[4];
                float2 b0 = r1[0], b1 = r1[1], b2 = r1[2], b3 = r1[3], b4 = r1[4];
                float2 c0 = r2[0], c1 = r2[1], c2 = r2[2], c3 = r2[3], c4 = r2[4];
                float2 d0 = r3[0], d1 = r3[1], d2 = r3[2], d3 = r3[3], d4 = r3[4];
                if ((int)k0 != curKey) { FLUSH_ACC(); curKey = (int)k0; ZERO_ACC(); }
                ACC10(a0, a1, a2, a3, a4);
                if ((int)k1 != curKey) { FLUSH_ACC(); curKey = (int)k1; ZERO_ACC(); }
                ACC10(b0, b1, b2, b3, b4);
                if ((int)k2 != curKey) { FLUSH_ACC(); curKey = (int)k2; ZERO_ACC(); }
                ACC10(c0, c1, c2, c3, c4);
                if ((int)k3 != curKey) { FLUSH_ACC(); curKey = (int)k3; ZERO_ACC(); }
                ACC10(d0, d1, d2, d3, d4);
            }
            for (; i < i1; i++) {
                unsigned p0 = sbuf[i];
                unsigned k0 = p0 & KM;
                const float2* r0 = (const float2*)(fsrc + (size_t)(rbase[k0] + (p0 >> KSH)) * F);
                float2 a0 = r0[0], a1 = r0[1], a2 = r0[2], a3 = r0[3], a4 = r0[4];
                if ((int)k0 != curKey) { FLUSH_ACC(); curKey = (int)k0; ZERO_ACC(); }
                ACC10(a0, a1, a2, a3, a4);
            }
            FLUSH_ACC();
#undef FLUSH_ACC
#undef ZERO_ACC
#undef ACC10
        }
    } else {
        // overflow fallback (statistically unreachable): per-edge atomics
        for (unsigned e = lo + tid; e < hi; e += BSZ) {
            unsigned pay = sorted[e];
            unsigned l = pay & KM, s = pay >> KSH;
            const float2* row = (const float2*)(fsrc + (size_t)(rbase[l] + s) * F);
            float* a = acc + l * ASTR;
#pragma unroll
            for (int k = 0; k < 5; k++) {
                float2 v = row[k];
                atomicAdd(a + 2 * k, v.x);
                atomicAdd(a + 2 * k + 1, v.y);
            }
            atomicAdd(&hist[l], 1u);
        }
    }
    __syncthreads();

    // epilogue: fused projection
    const float* fdst = isU ? fdst_u : fdst_i;
    const float* wsf = isU ? wsf_u : wsf_i;
    const float* wnf = isU ? wnf_u : wnf_i;
    const float* bia = isU ? bia_u : bia_i;
    float* out = isU ? out_u : out_i;

    int tot = (int)NKEY * D;
    for (int o = tid; o < tot; o += BSZ) {
        int local = o / D, d = o - local * D;
        unsigned key = keybase + (unsigned)local;
        if (key >= (unsigned)(R)*N) continue;
        unsigned r = key / N, n = key - r * N;
        float inv = 1.f / fmaxf((float)hist[local], 1.f);
        const float* fd = fdst + ((size_t)r * N + n) * F;
        const float* a = acc + local * ASTR;
        const float* wsp = wsf + (size_t)r * F * D + d;
        const float* wnp = wnf + (size_t)r * F * D + d;
        float o1 = bia[r * D + d], o2 = 0.f;
#pragma unroll
        for (int f = 0; f < F; f++) {
            o1 += fd[f] * wsp[(size_t)f * D];
            o2 += a[f] * wnp[(size_t)f * D];
        }
        out[(size_t)n * (R * D) + r * D + d] = o1 + o2 * inv;
    }
}

// ======================= round-1 fallback (small ws) =======================
#define SUM_I_OFF 0
#define CNT_I_OFF ((size_t)R * M * F)
#define SUM_U_OFF (CNT_I_OFF + (size_t)R * M)
#define CNT_U_OFF (SUM_U_OFF + (size_t)R * U * F)
#define WS_FLOATS (CNT_U_OFF + (size_t)R * U)

__global__ void scatter_edges(const int* __restrict__ esrc, const int* __restrict__ edst,
                              const float* __restrict__ feat_u_fwd,
                              const float* __restrict__ feat_i_rev, float* __restrict__ ws) {
    float* sum_i = ws + SUM_I_OFF;
    float* cnt_i = ws + CNT_I_OFF;
    float* sum_u = ws + SUM_U_OFF;
    float* cnt_u = ws + CNT_U_OFF;
    const int total = R * E;
    for (int idx = blockIdx.x * blockDim.x + threadIdx.x; idx < total;
         idx += gridDim.x * blockDim.x) {
        int r = idx / E;
        int s = esrc[idx], d = edst[idx];
        const float* fu = feat_u_fwd + ((size_t)r * U + s) * F;
        const float* fi = feat_i_rev + ((size_t)r * M + d) * F;
        float* si = sum_i + ((size_t)r * M + d) * F;
        float* su = sum_u + ((size_t)r * U + s) * F;
#pragma unroll
        for (int f = 0; f < F; ++f) {
            atomicAdd(si + f, fu[f]);
            atomicAdd(su + f, fi[f]);
        }
        atomicAdd(cnt_i + (size_t)r * M + d, 1.0f);
        atomicAdd(cnt_u + (size_t)r * U + s, 1.0f);
    }
}

__global__ void finalize_nodes(int N, const float* __restrict__ feat_dst,
                               const float* __restrict__ w_self, const float* __restrict__ w_neigh,
                               const float* __restrict__ bias, const float* __restrict__ sum,
                               const float* __restrict__ cnt, float* __restrict__ out) {
    int idx = blockIdx.x * blockDim.x + threadIdx.x;
    int total = N * R * D;
    if (idx >= total) return;
    int n = idx / (R * D);
    int rd = idx - n * (R * D);
    int r = rd / D;
    int d = rd - r * D;
    const float* fd = feat_dst + ((size_t)r * N + n) * F;
    const float* sn = sum + ((size_t)r * N + n) * F;
    float inv = 1.0f / fmaxf(cnt[(size_t)r * N + n], 1.0f);
    const float* wsp = w_self + (size_t)r * F * D + d;
    const float* wnp = w_neigh + (size_t)r * F * D + d;
    float acc_self = bias[r * D + d];
    float acc_n = 0.0f;
#pragma unroll
    for (int f = 0; f < F; ++f) {
        acc_self += fd[f] * wsp[(size_t)f * D];
        acc_n += sn[f] * wnp[(size_t)f * D];
    }
    out[idx] = acc_self + acc_n * inv;
}

// ======================= launch =======================
extern "C" void kernel_launch(void* const* d_in, const int* in_sizes, int n_in,
                              void* d_out, int out_size, void* d_ws, size_t ws_size,
                              hipStream_t stream) {
    const int* edges_src = (const int*)d_in[0];
    const int* edges_dst = (const int*)d_in[1];
    const float* feat_u_fwd = (const float*)d_in[2];
    const float* feat_i_fwd = (const float*)d_in[3];
    const float* feat_i_rev = (const float*)d_in[4];
    const float* feat_u_rev = (const float*)d_in[5];
    const float* w_self_fwd = (const float*)d_in[6];
    const float* w_neigh_fwd = (const float*)d_in[7];
    const float* b_fwd = (const float*)d_in[8];
    const float* w_self_rev = (const float*)d_in[9];
    const float* w_neigh_rev = (const float*)d_in[10];
    const float* b_rev = (const float*)d_in[11];

    float* out = (float*)d_out;
    float* out_u = out;
    float* out_i = out + (size_t)U * R * D;

    // sorted (2*TE) + S/ghist in-place (GTOT) + psum (2048)  ~= 86.0 MB
    size_t need = ((size_t)2 * TE + (size_t)GTOT + 2048ull) * 4ull;
    if (ws_size >= need) {
        unsigned* sorted = (unsigned*)d_ws;
        unsigned* S = sorted + (size_t)2 * TE;
        unsigned* psum = S + GTOT;

        phaseA<<<NBLK, BSZ_AC, 0, stream>>>(edges_src, edges_dst, S);
        scan1<<<NS1, BSZ, 0, stream>>>(S, psum);
        scan2<<<1, BSZ, 0, stream>>>(psum);
        scan3<<<NS1, BSZ, 0, stream>>>(S, psum);
        phaseC<<<NBLK, BSZ_AC, 0, stream>>>(edges_src, edges_dst, S, sorted);
        phaseD<<<NBU_T, BSZ, 0, stream>>>(sorted, S,
                                          feat_i_rev, feat_u_rev, w_self_rev, w_neigh_rev, b_rev,
                                          feat_u_fwd, feat_i_fwd, w_self_fwd, w_neigh_fwd, b_fwd,
                                          out_u, out_i);
    } else {
        // fallback: round-1 global-atomic path
        float* ws = (float*)d_ws;
        hipMemsetAsync(d_ws, 0, WS_FLOATS * sizeof(float), stream);
        scatter_edges<<<4096, 256, 0, stream>>>(edges_src, edges_dst, feat_u_fwd, feat_i_rev, ws);
        finalize_nodes<<<(U * R * D + 255) / 256, 256, 0, stream>>>(
            U, feat_u_rev, w_self_rev, w_neigh_rev, b_rev, ws + SUM_U_OFF, ws + CNT_U_OFF, out_u);
        finalize_nodes<<<(M * R * D + 255) / 256, 256, 0, stream>>>(
            M, feat_i_fwd, w_self_fwd, w_neigh_fwd, b_fwd, ws + SUM_I_OFF, ws + CNT_I_OFF, out_i);
    }
}